// Round 1
// baseline (1197.729 us; speedup 1.0000x reference)
//
#include <hip/hip_runtime.h>
#include <stdint.h>

// Problem constants (match reference)
#define NN   100000   // nodes
#define FIN  500      // input features
#define HID  128      // hidden
#define KP1  512      // FIN padded to mult of 32 for MFMA K-loop
#define K2   256      // 2*HID (GEMM2 K)
#define NB2  48       // GEMM2 N padded (40 -> 48)
#define CO   40       // classes
#define SCH  1024     // scan chunk
#define NBLK 98       // ceil(NN/SCH)

typedef __attribute__((ext_vector_type(8))) short short8;
typedef __attribute__((ext_vector_type(4))) float float4v;
typedef __attribute__((address_space(3))) unsigned int as3_u32;
typedef __attribute__((address_space(1))) unsigned int as1_u32;

__device__ __forceinline__ unsigned short f2bf(float f) {
  unsigned u = __float_as_uint(f);
  u = u + 0x7fffu + ((u >> 16) & 1u);   // RNE
  return (unsigned short)(u >> 16);
}
__device__ __forceinline__ float bf2f(unsigned short s) {
  return __uint_as_float(((unsigned)s) << 16);
}
__device__ __forceinline__ void gl_lds16(const void* g, void* l) {
  __builtin_amdgcn_global_load_lds((const as1_u32*)g, (as3_u32*)l, 16, 0, 0);
}

// ---------------- graph preprocessing ----------------
__global__ void k_count(const int* __restrict__ tgt, int n, int* __restrict__ deg) {
  int e = blockIdx.x * 256 + threadIdx.x;
  if (e < n) atomicAdd(&deg[tgt[e]], 1);
}

__global__ void k_dinv(const int* __restrict__ ds, const int* __restrict__ dk,
                       float* __restrict__ os, float* __restrict__ ok) {
  int i = blockIdx.x * 256 + threadIdx.x;
  if (i < NN) {
    os[i] = rsqrtf((float)(ds[i] + 1));   // +1 = self loop; deg >= 1 always
    ok[i] = rsqrtf((float)(dk[i] + 1));
  }
}

__global__ void k_scan_partial(const int* __restrict__ cnt, int* __restrict__ part) {
  __shared__ int sd[256];
  int b = blockIdx.x, t = threadIdx.x;
  int base = b * SCH;
  int s = 0;
  for (int i = t; i < SCH; i += 256) { int idx = base + i; if (idx < NN) s += cnt[idx]; }
  sd[t] = s; __syncthreads();
  for (int off = 128; off > 0; off >>= 1) { if (t < off) sd[t] += sd[t + off]; __syncthreads(); }
  if (t == 0) part[b] = sd[0];
}

__global__ void k_scan_offsets(int* part) {
  if (threadIdx.x == 0 && blockIdx.x == 0) {
    int run = 0;
    for (int i = 0; i < NBLK; ++i) { int v = part[i]; part[i] = run; run += v; }
    part[NBLK] = run;
  }
}

__global__ void k_scan_write(const int* __restrict__ cnt, const int* __restrict__ part,
                             int* __restrict__ rp, int* __restrict__ cur) {
  __shared__ int sums[256];
  int b = blockIdx.x, t = threadIdx.x;
  int base = b * SCH + t * 4;
  int v0 = (base + 0 < NN) ? cnt[base + 0] : 0;
  int v1 = (base + 1 < NN) ? cnt[base + 1] : 0;
  int v2 = (base + 2 < NN) ? cnt[base + 2] : 0;
  int v3 = (base + 3 < NN) ? cnt[base + 3] : 0;
  int s = v0 + v1 + v2 + v3;
  sums[t] = s; __syncthreads();
  for (int off = 1; off < 256; off <<= 1) {   // Hillis-Steele inclusive scan
    int x = (t >= off) ? sums[t - off] : 0;
    __syncthreads();
    sums[t] += x;
    __syncthreads();
  }
  int excl = part[b] + sums[t] - s;
  if (base + 0 < NN) { rp[base + 0] = excl; cur[base + 0] = excl; excl += v0; }
  if (base + 1 < NN) { rp[base + 1] = excl; cur[base + 1] = excl; excl += v1; }
  if (base + 2 < NN) { rp[base + 2] = excl; cur[base + 2] = excl; excl += v2; }
  if (base + 3 < NN) { rp[base + 3] = excl; cur[base + 3] = excl; excl += v3; }
  if (b == 0 && t == 0) rp[NN] = part[NBLK];
}

__global__ void k_scatter(const int* __restrict__ src, const int* __restrict__ tgt, int n,
                          int* __restrict__ cur, int* __restrict__ col) {
  int e = blockIdx.x * 256 + threadIdx.x;
  if (e < n) {
    int c = tgt[e];
    int p = atomicAdd(&cur[c], 1);
    col[p] = src[e];
  }
}

// ---------------- weight convert/transpose ----------------
// W1T[n][k] bf16, n<128, k<512 (k>=500 zero) — B operand stored k-contiguous
__global__ void k_w1t(const float* __restrict__ W1, unsigned short* __restrict__ W1T) {
  int idx = blockIdx.x * 256 + threadIdx.x;      // 128*512
  int n = idx >> 9, k = idx & 511;
  float v = (k < FIN) ? W1[k * HID + n] : 0.f;
  W1T[idx] = f2bf(v);
}
// W2T[n][k] bf16, n<48 (n>=40 zero), k<256
__global__ void k_w2t(const float* __restrict__ W2, unsigned short* __restrict__ W2T) {
  int idx = blockIdx.x * 256 + threadIdx.x;      // 48*256
  int n = idx >> 8, k = idx & 255;
  float v = (n < CO) ? W2[k * CO + n] : 0.f;
  W2T[idx] = f2bf(v);
}

// ---------------- GEMM1: H1b = bf16(x @ W1)  [NN x 128] ----------------
__global__ __launch_bounds__(256) void k_gemm1(const float* __restrict__ x,
    const unsigned short* __restrict__ W1T, const float* __restrict__ zbuf,
    unsigned short* __restrict__ H1b) {
  __shared__ float Als[1024 * 4];          // chunk = kg4*128+m, 4 floats each (16B)
  __shared__ unsigned short Bls[512 * 8];  // chunk = kg8*128+n, 8 bf16 each (16B)
  const int t = threadIdx.x;
  const int wv = t >> 6, lane = t & 63;
  const int qd = lane >> 4, mr = lane & 15;
  const int m0 = blockIdx.x * 128;

  float4v acc[2][8];
  const float4v zf4 = {0.f, 0.f, 0.f, 0.f};
#pragma unroll
  for (int a = 0; a < 2; ++a)
#pragma unroll
    for (int b = 0; b < 8; ++b) acc[a][b] = zf4;

  for (int kk = 0; kk < 16; ++kk) {
    const int k0 = kk * 32;
    __syncthreads();
    // stage A (x fp32) — 16 x global_load_lds dwordx4, 4 per wave
#pragma unroll
    for (int i = 0; i < 4; ++i) {
      const int cb = (wv * 4 + i) * 64;
      const int q = cb + lane;
      const int kg = q >> 7, m = q & 127;
      const int gm = m0 + m, kb = k0 + kg * 4;   // 500 % 4 == 0 -> chunks never straddle
      const float* gp = (gm < NN && kb < FIN) ? (x + (size_t)gm * FIN + kb) : zbuf;
      gl_lds16(gp, &Als[cb * 4]);
    }
    // stage B (W1T bf16) — 8 instrs, 2 per wave
#pragma unroll
    for (int i = 0; i < 2; ++i) {
      const int cb = (wv * 2 + i) * 64;
      const int q = cb + lane;
      const int kg = q >> 7, n = q & 127;
      const unsigned short* gp = W1T + n * KP1 + k0 + kg * 8;
      gl_lds16(gp, &Bls[cb * 8]);
    }
    __syncthreads();
    short8 af[2];
#pragma unroll
    for (int rt = 0; rt < 2; ++rt) {   // A frag: A[m=lane&15][k=qd*8+j]
      const int m = wv * 32 + rt * 16 + mr;
      const float4v a0 = *(const float4v*)&Als[((2 * qd) * 128 + m) * 4];
      const float4v a1 = *(const float4v*)&Als[((2 * qd + 1) * 128 + m) * 4];
      short8 f;
      f[0] = (short)f2bf(a0[0]); f[1] = (short)f2bf(a0[1]);
      f[2] = (short)f2bf(a0[2]); f[3] = (short)f2bf(a0[3]);
      f[4] = (short)f2bf(a1[0]); f[5] = (short)f2bf(a1[1]);
      f[6] = (short)f2bf(a1[2]); f[7] = (short)f2bf(a1[3]);
      af[rt] = f;
    }
#pragma unroll
    for (int ct = 0; ct < 8; ++ct) {   // B frag: B[k=qd*8+j][n=lane&15]
      const short8 bf = *(const short8*)&Bls[(qd * 128 + ct * 16 + mr) * 8];
      acc[0][ct] = __builtin_amdgcn_mfma_f32_16x16x32_bf16(af[0], bf, acc[0][ct], 0, 0, 0);
      acc[1][ct] = __builtin_amdgcn_mfma_f32_16x16x32_bf16(af[1], bf, acc[1][ct], 0, 0, 0);
    }
  }
  // C/D layout: col = lane&15, row = (lane>>4)*4 + j   [m89/m91 verified]
#pragma unroll
  for (int rt = 0; rt < 2; ++rt) {
    const int rb = m0 + wv * 32 + rt * 16 + qd * 4;
#pragma unroll
    for (int ct = 0; ct < 8; ++ct) {
      const int col = ct * 16 + mr;
#pragma unroll
      for (int j = 0; j < 4; ++j) {
        const int r = rb + j;
        if (r < NN) H1b[(size_t)r * HID + col] = f2bf(acc[rt][ct][j]);
      }
    }
  }
}

// ---------------- GEMM2: H2b = bf16(R1b @ W2)  [NN x 40] ----------------
__global__ __launch_bounds__(256) void k_gemm2(const unsigned short* __restrict__ R1b,
    const unsigned short* __restrict__ W2T, const unsigned short* __restrict__ zbuf,
    unsigned short* __restrict__ H2b) {
  __shared__ unsigned short Als[512 * 8];  // chunk = kg8*128+m
  __shared__ unsigned short Bls[192 * 8];  // chunk = kg8*48+n
  const int t = threadIdx.x;
  const int wv = t >> 6, lane = t & 63;
  const int qd = lane >> 4, mr = lane & 15;
  const int m0 = blockIdx.x * 128;

  float4v acc[2][3];
  const float4v zf4 = {0.f, 0.f, 0.f, 0.f};
#pragma unroll
  for (int a = 0; a < 2; ++a)
#pragma unroll
    for (int b = 0; b < 3; ++b) acc[a][b] = zf4;

  for (int kk = 0; kk < 8; ++kk) {
    const int k0 = kk * 32;
    __syncthreads();
#pragma unroll
    for (int i = 0; i < 2; ++i) {
      const int cb = (wv * 2 + i) * 64;
      const int q = cb + lane;
      const int kg = q >> 7, m = q & 127;
      const int gm = m0 + m;
      const unsigned short* gp = (gm < NN) ? (R1b + (size_t)gm * K2 + k0 + kg * 8) : zbuf;
      gl_lds16(gp, &Als[cb * 8]);
    }
    if (wv < 3) {   // 192 chunks = 3 wave-instrs
      const int cb = wv * 64;
      const int q = cb + lane;
      const int kg = q / 48, n = q % 48;
      const unsigned short* gp = W2T + n * K2 + k0 + kg * 8;
      gl_lds16(gp, &Bls[cb * 8]);
    }
    __syncthreads();
    short8 af[2];
#pragma unroll
    for (int rt = 0; rt < 2; ++rt)
      af[rt] = *(const short8*)&Als[(qd * 128 + wv * 32 + rt * 16 + mr) * 8];
#pragma unroll
    for (int ct = 0; ct < 3; ++ct) {
      const short8 bf = *(const short8*)&Bls[(qd * 48 + ct * 16 + mr) * 8];
      acc[0][ct] = __builtin_amdgcn_mfma_f32_16x16x32_bf16(af[0], bf, acc[0][ct], 0, 0, 0);
      acc[1][ct] = __builtin_amdgcn_mfma_f32_16x16x32_bf16(af[1], bf, acc[1][ct], 0, 0, 0);
    }
  }
#pragma unroll
  for (int rt = 0; rt < 2; ++rt) {
    const int rb = m0 + wv * 32 + rt * 16 + qd * 4;
#pragma unroll
    for (int ct = 0; ct < 3; ++ct) {
      const int col = ct * 16 + mr;
      if (col < CO) {
#pragma unroll
        for (int j = 0; j < 4; ++j) {
          const int r = rb + j;
          if (r < NN) H2b[(size_t)r * CO + col] = f2bf(acc[rt][ct][j]);
        }
      }
    }
  }
}

// ---------------- layer-1 aggregation: wave per target node, 128 cols ----------------
__global__ __launch_bounds__(256) void k_agg1(const int* __restrict__ rp,
    const int* __restrict__ ci, const float* __restrict__ dinv,
    const unsigned short* __restrict__ H, const float* __restrict__ bias,
    unsigned short* __restrict__ out, int colOff) {
  const int wv = threadIdx.x >> 6, lane = threadIdx.x & 63;
  const int c = blockIdx.x * 4 + wv;
  if (c >= NN) return;
  const float dc = dinv[c];
  const unsigned pc = ((const unsigned*)(H + (size_t)c * HID))[lane];
  float ax = dc * bf2f((unsigned short)(pc & 0xffffu));   // self loop: H[c]*dinv[c]
  float ay = dc * bf2f((unsigned short)(pc >> 16));
  int e = rp[c];
  const int e1 = rp[c + 1];
  for (; e + 4 <= e1; e += 4) {
    const int r0 = ci[e], r1 = ci[e + 1], r2 = ci[e + 2], r3 = ci[e + 3];
    const float d0 = dinv[r0], d1 = dinv[r1], d2 = dinv[r2], d3 = dinv[r3];
    const unsigned p0 = ((const unsigned*)(H + (size_t)r0 * HID))[lane];
    const unsigned p1 = ((const unsigned*)(H + (size_t)r1 * HID))[lane];
    const unsigned p2 = ((const unsigned*)(H + (size_t)r2 * HID))[lane];
    const unsigned p3 = ((const unsigned*)(H + (size_t)r3 * HID))[lane];
    ax += d0 * bf2f((unsigned short)(p0 & 0xffffu)) + d1 * bf2f((unsigned short)(p1 & 0xffffu))
        + d2 * bf2f((unsigned short)(p2 & 0xffffu)) + d3 * bf2f((unsigned short)(p3 & 0xffffu));
    ay += d0 * bf2f((unsigned short)(p0 >> 16)) + d1 * bf2f((unsigned short)(p1 >> 16))
        + d2 * bf2f((unsigned short)(p2 >> 16)) + d3 * bf2f((unsigned short)(p3 >> 16));
  }
  for (; e < e1; ++e) {
    const int r = ci[e];
    const float d = dinv[r];
    const unsigned pr = ((const unsigned*)(H + (size_t)r * HID))[lane];
    ax += d * bf2f((unsigned short)(pr & 0xffffu));
    ay += d * bf2f((unsigned short)(pr >> 16));
  }
  const float2 b = ((const float2*)bias)[lane];
  const float o0 = fmaxf(dc * ax + b.x, 0.f);   // relu (layer-1 only)
  const float o1 = fmaxf(dc * ay + b.y, 0.f);
  const unsigned pk = (unsigned)f2bf(o0) | ((unsigned)f2bf(o1) << 16);
  ((unsigned*)(out + (size_t)c * (2 * HID) + colOff))[lane] = pk;
}

// ---------------- layer-2 aggregation: wave per node, lanes 0..39 ----------------
__global__ __launch_bounds__(256) void k_agg2(const int* __restrict__ rp,
    const int* __restrict__ ci, const float* __restrict__ dinv,
    const unsigned short* __restrict__ H2, const float* __restrict__ bias,
    float* __restrict__ R2, int colOff) {
  const int wv = threadIdx.x >> 6, lane = threadIdx.x & 63;
  const int c = blockIdx.x * 4 + wv;
  if (c >= NN || lane >= CO) return;
  const float dc = dinv[c];
  float acc = dc * bf2f(H2[(size_t)c * CO + lane]);
  int e = rp[c];
  const int e1 = rp[c + 1];
  for (; e + 4 <= e1; e += 4) {
    const int r0 = ci[e], r1 = ci[e + 1], r2 = ci[e + 2], r3 = ci[e + 3];
    const float d0 = dinv[r0], d1 = dinv[r1], d2 = dinv[r2], d3 = dinv[r3];
    const float h0 = bf2f(H2[(size_t)r0 * CO + lane]);
    const float h1 = bf2f(H2[(size_t)r1 * CO + lane]);
    const float h2 = bf2f(H2[(size_t)r2 * CO + lane]);
    const float h3 = bf2f(H2[(size_t)r3 * CO + lane]);
    acc += d0 * h0 + d1 * h1 + d2 * h2 + d3 * h3;
  }
  for (; e < e1; ++e) {
    const int r = ci[e];
    acc += dinv[r] * bf2f(H2[(size_t)r * CO + lane]);
  }
  R2[(size_t)c * 80 + colOff + lane] = dc * acc + bias[lane];   // no relu on layer 2
}

// ---------------- head: logits = R2 @ Wlin^T + blin; log_softmax ----------------
__global__ __launch_bounds__(256) void k_final(const float* __restrict__ R2,
    const float* __restrict__ Wlin, const float* __restrict__ blin,
    float* __restrict__ out) {
  __shared__ float rw[32 * 81];   // 32 nodes x 80 (+1 pad)
  __shared__ float wl[40 * 81];   // 40 x 80 (+1 pad)
  __shared__ float bl[40];
  const int t = threadIdx.x;
  const int n0 = blockIdx.x * 32;   // 3125*32 = 100000 exactly
  for (int i = t; i < 2560; i += 256) rw[(i / 80) * 81 + (i % 80)] = R2[(size_t)n0 * 80 + i];
  for (int i = t; i < 3200; i += 256) wl[(i / 80) * 81 + (i % 80)] = Wlin[i];
  if (t < 40) bl[t] = blin[t];
  __syncthreads();
  const int nl = t >> 3, jg = t & 7;
  const int j0 = jg * 5;
  float lg[5];
#pragma unroll
  for (int jj = 0; jj < 5; ++jj) lg[jj] = bl[j0 + jj];
#pragma unroll 4
  for (int k = 0; k < 80; ++k) {
    const float v = rw[nl * 81 + k];
#pragma unroll
    for (int jj = 0; jj < 5; ++jj) lg[jj] += v * wl[(j0 + jj) * 81 + k];
  }
  float mx = lg[0];
#pragma unroll
  for (int jj = 1; jj < 5; ++jj) mx = fmaxf(mx, lg[jj]);
  mx = fmaxf(mx, __shfl_xor(mx, 1));
  mx = fmaxf(mx, __shfl_xor(mx, 2));
  mx = fmaxf(mx, __shfl_xor(mx, 4));
  float s = 0.f;
#pragma unroll
  for (int jj = 0; jj < 5; ++jj) s += expf(lg[jj] - mx);
  s += __shfl_xor(s, 1);
  s += __shfl_xor(s, 2);
  s += __shfl_xor(s, 4);
  const float lse = mx + logf(s);
  const int n = n0 + nl;
#pragma unroll
  for (int jj = 0; jj < 5; ++jj) out[(size_t)n * CO + j0 + jj] = lg[jj] - lse;
}

extern "C" void kernel_launch(void* const* d_in, const int* in_sizes, int n_in,
                              void* d_out, int out_size, void* d_ws, size_t ws_size,
                              hipStream_t stream) {
  const float* x  = (const float*)d_in[0];
  const int* ei   = (const int*)d_in[1];   // [2][E]: row0 = src, row1 = tgt
  const int* eik  = (const int*)d_in[2];
  const float* W1 = (const float*)d_in[3];
  const float* b1 = (const float*)d_in[4];
  const float* W2 = (const float*)d_in[5];
  const float* b2 = (const float*)d_in[6];
  const float* Wl = (const float*)d_in[7];
  const float* bl = (const float*)d_in[8];
  float* out = (float*)d_out;
  const int E  = in_sizes[1] / 2;
  const int EK = in_sizes[2] / 2;

  // workspace layout (~135 MB), 256B-aligned slots
  char* p = (char*)d_ws;
  size_t off = 0;
  auto alloc = [&](size_t bytes) -> void* {
    void* r = (void*)(p + off);
    off += (bytes + 255) & ~(size_t)255;
    return r;
  };
  int* deg_s = (int*)alloc((size_t)NN * 4);
  int* deg_k = (int*)alloc((size_t)NN * 4);
  void* zbuf = alloc(256);                 // zero redirect target for OOB tiles
  const size_t zero_span = off;            // memset covers deg_s, deg_k, zbuf
  float* dinv_s = (float*)alloc((size_t)NN * 4);
  float* dinv_k = (float*)alloc((size_t)NN * 4);
  int* rp_s  = (int*)alloc((size_t)(NN + 1) * 4);
  int* rp_k  = (int*)alloc((size_t)(NN + 1) * 4);
  int* cur_s = (int*)alloc((size_t)NN * 4);
  int* cur_k = (int*)alloc((size_t)NN * 4);
  int* part_s = (int*)alloc(4096);
  int* part_k = (int*)alloc(4096);
  unsigned short* W1T = (unsigned short*)alloc((size_t)HID * KP1 * 2);
  unsigned short* W2T = (unsigned short*)alloc((size_t)NB2 * K2 * 2);
  int* col_s = (int*)alloc((size_t)E * 4);
  int* col_k = (int*)alloc((size_t)EK * 4);
  unsigned short* H1b = (unsigned short*)alloc((size_t)NN * HID * 2);
  unsigned short* R1b = (unsigned short*)alloc((size_t)NN * K2 * 2);
  unsigned short* H2b = (unsigned short*)alloc((size_t)NN * CO * 2);
  float* R2 = (float*)alloc((size_t)NN * 80 * 4);

  hipMemsetAsync(d_ws, 0, zero_span, stream);

  // CSR build (by target) for both graphs
  k_count<<<(E + 255) / 256, 256, 0, stream>>>(ei + E, E, deg_s);
  k_count<<<(EK + 255) / 256, 256, 0, stream>>>(eik + EK, EK, deg_k);
  k_dinv<<<(NN + 255) / 256, 256, 0, stream>>>(deg_s, deg_k, dinv_s, dinv_k);
  k_scan_partial<<<NBLK, 256, 0, stream>>>(deg_s, part_s);
  k_scan_offsets<<<1, 64, 0, stream>>>(part_s);
  k_scan_write<<<NBLK, 256, 0, stream>>>(deg_s, part_s, rp_s, cur_s);
  k_scan_partial<<<NBLK, 256, 0, stream>>>(deg_k, part_k);
  k_scan_offsets<<<1, 64, 0, stream>>>(part_k);
  k_scan_write<<<NBLK, 256, 0, stream>>>(deg_k, part_k, rp_k, cur_k);
  k_scatter<<<(E + 255) / 256, 256, 0, stream>>>(ei, ei + E, E, cur_s, col_s);
  k_scatter<<<(EK + 255) / 256, 256, 0, stream>>>(eik, eik + EK, EK, cur_k, col_k);

  // weights -> bf16, B-operand (k-contiguous) layout
  k_w1t<<<(HID * KP1) / 256, 256, 0, stream>>>(W1, W1T);
  k_w2t<<<(NB2 * K2) / 256, 256, 0, stream>>>(W2, W2T);

  // layer 1: shared GEMM, two aggregations into R1b halves
  k_gemm1<<<(NN + 127) / 128, 256, 0, stream>>>(x, W1T, (const float*)zbuf, H1b);
  k_agg1<<<(NN + 3) / 4, 256, 0, stream>>>(rp_s, col_s, dinv_s, H1b, b1, R1b, 0);
  k_agg1<<<(NN + 3) / 4, 256, 0, stream>>>(rp_k, col_k, dinv_k, H1b, b1, R1b, HID);

  // layer 2: shared GEMM, two aggregations into R2 halves
  k_gemm2<<<(NN + 127) / 128, 256, 0, stream>>>(R1b, W2T, (const unsigned short*)zbuf, H2b);
  k_agg2<<<(NN + 3) / 4, 256, 0, stream>>>(rp_s, col_s, dinv_s, H2b, b2, R2, 0);
  k_agg2<<<(NN + 3) / 4, 256, 0, stream>>>(rp_k, col_k, dinv_k, H2b, b2, R2, CO);

  // head
  k_final<<<NN / 32, 256, 0, stream>>>(R2, Wl, bl, out);
}

// Round 2
// 947.161 us; speedup vs baseline: 1.2645x; 1.2645x over previous
//
#include <hip/hip_runtime.h>
#include <stdint.h>

// Problem constants (match reference)
#define NN   100000   // nodes
#define FIN  500      // input features
#define HID  128      // hidden
#define KP1  512      // FIN padded to mult of 32 for MFMA K-loop
#define K2   256      // 2*HID (GEMM2 K)
#define CO   40       // classes
#define SLOT_S 80     // slot capacity structural (deg ~ Poisson(32))
#define SLOT_K 24     // slot capacity knn (deg ~ Poisson(5))

typedef __attribute__((ext_vector_type(8))) short short8;
typedef __attribute__((ext_vector_type(4))) float float4v;
typedef __attribute__((address_space(3))) unsigned int as3_u32;
typedef __attribute__((address_space(1))) unsigned int as1_u32;

__device__ __forceinline__ unsigned short f2bf(float f) {
  unsigned u = __float_as_uint(f);
  u = u + 0x7fffu + ((u >> 16) & 1u);   // RNE
  return (unsigned short)(u >> 16);
}
__device__ __forceinline__ float bf2f(unsigned short s) {
  return __uint_as_float(((unsigned)s) << 16);
}
__device__ __forceinline__ void gl_lds16(const void* g, void* l) {
  __builtin_amdgcn_global_load_lds((const as1_u32*)g, (as3_u32*)l, 16, 0, 0);
}

// ---------------- single-pass slotted scatter (count + place), both graphs ----------------
__global__ __launch_bounds__(256) void k_slot(
    const int* __restrict__ ei, int nS, int nbS, int* __restrict__ cnt_s, int* __restrict__ slots_s,
    const int* __restrict__ eik, int nK, int* __restrict__ cnt_k, int* __restrict__ slots_k) {
  const int b = blockIdx.x;
  const bool knn = (b >= nbS);
  const int* src = knn ? eik      : ei;
  const int* tgt = knn ? eik + nK : ei + nS;
  const int n    = knn ? nK : nS;
  int* cnt       = knn ? cnt_k : cnt_s;
  int* slots     = knn ? slots_k : slots_s;
  const int cap  = knn ? SLOT_K : SLOT_S;
  const int bb   = knn ? b - nbS : b;

  const int e0 = (bb * 256 + threadIdx.x) * 4;
  int c[4], s[4], p[4];
#pragma unroll
  for (int i = 0; i < 4; ++i) {
    const int e = e0 + i;
    const bool v = e < n;
    c[i] = v ? tgt[e] : 0;
    s[i] = v ? src[e] : 0;
    p[i] = v ? atomicAdd(&cnt[c[i]], 1) : 0x7fffffff;
  }
#pragma unroll
  for (int i = 0; i < 4; ++i)
    if (p[i] < cap) slots[(size_t)c[i] * cap + p[i]] = s[i];
}

__global__ void k_dinv(const int* __restrict__ ds, const int* __restrict__ dk,
                       float* __restrict__ os, float* __restrict__ ok) {
  int i = blockIdx.x * 256 + threadIdx.x;
  if (i < NN) {
    os[i] = rsqrtf((float)(ds[i] + 1));   // +1 = self loop; deg >= 1 always
    ok[i] = rsqrtf((float)(dk[i] + 1));
  }
}

// ---------------- weight convert/transpose ----------------
__global__ void k_w1t(const float* __restrict__ W1, unsigned short* __restrict__ W1T) {
  int idx = blockIdx.x * 256 + threadIdx.x;      // 128*512
  int n = idx >> 9, k = idx & 511;
  float v = (k < FIN) ? W1[k * HID + n] : 0.f;
  W1T[idx] = f2bf(v);
}
__global__ void k_w2t(const float* __restrict__ W2, unsigned short* __restrict__ W2T) {
  int idx = blockIdx.x * 256 + threadIdx.x;      // 48*256
  int n = idx >> 8, k = idx & 255;
  float v = (n < CO) ? W2[k * CO + n] : 0.f;
  W2T[idx] = f2bf(v);
}

// ---------------- GEMM1: H1b = bf16(x @ W1)  [NN x 128] ----------------
__global__ __launch_bounds__(256) void k_gemm1(const float* __restrict__ x,
    const unsigned short* __restrict__ W1T, const float* __restrict__ zbuf,
    unsigned short* __restrict__ H1b) {
  __shared__ float Als[1024 * 4];          // chunk = kg4*128+m, 4 floats each (16B)
  __shared__ unsigned short Bls[512 * 8];  // chunk = kg8*128+n, 8 bf16 each (16B)
  const int t = threadIdx.x;
  const int wv = t >> 6, lane = t & 63;
  const int qd = lane >> 4, mr = lane & 15;
  const int m0 = blockIdx.x * 128;

  float4v acc[2][8];
  const float4v zf4 = {0.f, 0.f, 0.f, 0.f};
#pragma unroll
  for (int a = 0; a < 2; ++a)
#pragma unroll
    for (int b = 0; b < 8; ++b) acc[a][b] = zf4;

  for (int kk = 0; kk < 16; ++kk) {
    const int k0 = kk * 32;
    __syncthreads();
#pragma unroll
    for (int i = 0; i < 4; ++i) {
      const int cb = (wv * 4 + i) * 64;
      const int q = cb + lane;
      const int kg = q >> 7, m = q & 127;
      const int gm = m0 + m, kb = k0 + kg * 4;   // 500 % 4 == 0 -> never straddles
      const float* gp = (gm < NN && kb < FIN) ? (x + (size_t)gm * FIN + kb) : zbuf;
      gl_lds16(gp, &Als[cb * 4]);
    }
#pragma unroll
    for (int i = 0; i < 2; ++i) {
      const int cb = (wv * 2 + i) * 64;
      const int q = cb + lane;
      const int kg = q >> 7, n = q & 127;
      const unsigned short* gp = W1T + n * KP1 + k0 + kg * 8;
      gl_lds16(gp, &Bls[cb * 8]);
    }
    __syncthreads();
    short8 af[2];
#pragma unroll
    for (int rt = 0; rt < 2; ++rt) {   // A frag: A[m=lane&15][k=qd*8+j]
      const int m = wv * 32 + rt * 16 + mr;
      const float4v a0 = *(const float4v*)&Als[((2 * qd) * 128 + m) * 4];
      const float4v a1 = *(const float4v*)&Als[((2 * qd + 1) * 128 + m) * 4];
      short8 f;
      f[0] = (short)f2bf(a0[0]); f[1] = (short)f2bf(a0[1]);
      f[2] = (short)f2bf(a0[2]); f[3] = (short)f2bf(a0[3]);
      f[4] = (short)f2bf(a1[0]); f[5] = (short)f2bf(a1[1]);
      f[6] = (short)f2bf(a1[2]); f[7] = (short)f2bf(a1[3]);
      af[rt] = f;
    }
#pragma unroll
    for (int ct = 0; ct < 8; ++ct) {   // B frag: B[k=qd*8+j][n=lane&15]
      const short8 bf = *(const short8*)&Bls[(qd * 128 + ct * 16 + mr) * 8];
      acc[0][ct] = __builtin_amdgcn_mfma_f32_16x16x32_bf16(af[0], bf, acc[0][ct], 0, 0, 0);
      acc[1][ct] = __builtin_amdgcn_mfma_f32_16x16x32_bf16(af[1], bf, acc[1][ct], 0, 0, 0);
    }
  }
  // C/D layout: col = lane&15, row = (lane>>4)*4 + j
#pragma unroll
  for (int rt = 0; rt < 2; ++rt) {
    const int rb = m0 + wv * 32 + rt * 16 + qd * 4;
#pragma unroll
    for (int ct = 0; ct < 8; ++ct) {
      const int col = ct * 16 + mr;
#pragma unroll
      for (int j = 0; j < 4; ++j) {
        const int r = rb + j;
        if (r < NN) H1b[(size_t)r * HID + col] = f2bf(acc[rt][ct][j]);
      }
    }
  }
}

// ---------------- GEMM2: H2b = bf16(R1b @ W2)  [NN x 40] ----------------
__global__ __launch_bounds__(256) void k_gemm2(const unsigned short* __restrict__ R1b,
    const unsigned short* __restrict__ W2T, const unsigned short* __restrict__ zbuf,
    unsigned short* __restrict__ H2b) {
  __shared__ unsigned short Als[512 * 8];  // chunk = kg8*128+m
  __shared__ unsigned short Bls[192 * 8];  // chunk = kg8*48+n
  const int t = threadIdx.x;
  const int wv = t >> 6, lane = t & 63;
  const int qd = lane >> 4, mr = lane & 15;
  const int m0 = blockIdx.x * 128;

  float4v acc[2][3];
  const float4v zf4 = {0.f, 0.f, 0.f, 0.f};
#pragma unroll
  for (int a = 0; a < 2; ++a)
#pragma unroll
    for (int b = 0; b < 3; ++b) acc[a][b] = zf4;

  for (int kk = 0; kk < 8; ++kk) {
    const int k0 = kk * 32;
    __syncthreads();
#pragma unroll
    for (int i = 0; i < 2; ++i) {
      const int cb = (wv * 2 + i) * 64;
      const int q = cb + lane;
      const int kg = q >> 7, m = q & 127;
      const int gm = m0 + m;
      const unsigned short* gp = (gm < NN) ? (R1b + (size_t)gm * K2 + k0 + kg * 8) : zbuf;
      gl_lds16(gp, &Als[cb * 8]);
    }
    if (wv < 3) {   // 192 chunks = 3 wave-instrs
      const int cb = wv * 64;
      const int q = cb + lane;
      const int kg = q / 48, n = q % 48;
      const unsigned short* gp = W2T + n * K2 + k0 + kg * 8;
      gl_lds16(gp, &Bls[cb * 8]);
    }
    __syncthreads();
    short8 af[2];
#pragma unroll
    for (int rt = 0; rt < 2; ++rt)
      af[rt] = *(const short8*)&Als[(qd * 128 + wv * 32 + rt * 16 + mr) * 8];
#pragma unroll
    for (int ct = 0; ct < 3; ++ct) {
      const short8 bf = *(const short8*)&Bls[(qd * 48 + ct * 16 + mr) * 8];
      acc[0][ct] = __builtin_amdgcn_mfma_f32_16x16x32_bf16(af[0], bf, acc[0][ct], 0, 0, 0);
      acc[1][ct] = __builtin_amdgcn_mfma_f32_16x16x32_bf16(af[1], bf, acc[1][ct], 0, 0, 0);
    }
  }
#pragma unroll
  for (int rt = 0; rt < 2; ++rt) {
    const int rb = m0 + wv * 32 + rt * 16 + qd * 4;
#pragma unroll
    for (int ct = 0; ct < 3; ++ct) {
      const int col = ct * 16 + mr;
      if (col < CO) {
#pragma unroll
        for (int j = 0; j < 4; ++j) {
          const int r = rb + j;
          if (r < NN) H2b[(size_t)r * CO + col] = f2bf(acc[rt][ct][j]);
        }
      }
    }
  }
}

// ---------------- layer-1 aggregation (both graphs fused): wave per node, 128 cols ----------------
__global__ __launch_bounds__(256) void k_agg1(
    const int* __restrict__ cnt_s, const int* __restrict__ slots_s, const float* __restrict__ dinv_s,
    const int* __restrict__ cnt_k, const int* __restrict__ slots_k, const float* __restrict__ dinv_k,
    const unsigned short* __restrict__ H, const float* __restrict__ bias,
    unsigned short* __restrict__ out, int nbS) {
  const int b = blockIdx.x;
  const bool knn = (b >= nbS);
  const int* cnt = knn ? cnt_k : cnt_s;
  const int* slots = knn ? slots_k : slots_s;
  const float* dinv = knn ? dinv_k : dinv_s;
  const int cap = knn ? SLOT_K : SLOT_S;
  const int colOff = knn ? HID : 0;
  const int wv = threadIdx.x >> 6, lane = threadIdx.x & 63;
  const int c = (knn ? b - nbS : b) * 4 + wv;
  if (c >= NN) return;
  const float dc = dinv[c];
  const unsigned pc = ((const unsigned*)(H + (size_t)c * HID))[lane];
  float ax = dc * bf2f((unsigned short)(pc & 0xffffu));   // self loop
  float ay = dc * bf2f((unsigned short)(pc >> 16));
  int n = cnt[c]; if (n > cap) n = cap;
  const int* sl = slots + (size_t)c * cap;
  int e = 0;
  for (; e + 4 <= n; e += 4) {
    const int r0 = sl[e], r1 = sl[e + 1], r2 = sl[e + 2], r3 = sl[e + 3];
    const float d0 = dinv[r0], d1 = dinv[r1], d2 = dinv[r2], d3 = dinv[r3];
    const unsigned p0 = ((const unsigned*)(H + (size_t)r0 * HID))[lane];
    const unsigned p1 = ((const unsigned*)(H + (size_t)r1 * HID))[lane];
    const unsigned p2 = ((const unsigned*)(H + (size_t)r2 * HID))[lane];
    const unsigned p3 = ((const unsigned*)(H + (size_t)r3 * HID))[lane];
    ax += d0 * bf2f((unsigned short)(p0 & 0xffffu)) + d1 * bf2f((unsigned short)(p1 & 0xffffu))
        + d2 * bf2f((unsigned short)(p2 & 0xffffu)) + d3 * bf2f((unsigned short)(p3 & 0xffffu));
    ay += d0 * bf2f((unsigned short)(p0 >> 16)) + d1 * bf2f((unsigned short)(p1 >> 16))
        + d2 * bf2f((unsigned short)(p2 >> 16)) + d3 * bf2f((unsigned short)(p3 >> 16));
  }
  for (; e < n; ++e) {
    const int r = sl[e];
    const float d = dinv[r];
    const unsigned pr = ((const unsigned*)(H + (size_t)r * HID))[lane];
    ax += d * bf2f((unsigned short)(pr & 0xffffu));
    ay += d * bf2f((unsigned short)(pr >> 16));
  }
  const float2 bb = ((const float2*)bias)[lane];
  const float o0 = fmaxf(dc * ax + bb.x, 0.f);   // relu
  const float o1 = fmaxf(dc * ay + bb.y, 0.f);
  const unsigned pk = (unsigned)f2bf(o0) | ((unsigned)f2bf(o1) << 16);
  ((unsigned*)(out + (size_t)c * (2 * HID) + colOff))[lane] = pk;
}

// ---------------- layer-2 aggregation (both graphs fused): wave per node, lanes 0..39 ----------------
__global__ __launch_bounds__(256) void k_agg2(
    const int* __restrict__ cnt_s, const int* __restrict__ slots_s, const float* __restrict__ dinv_s,
    const int* __restrict__ cnt_k, const int* __restrict__ slots_k, const float* __restrict__ dinv_k,
    const unsigned short* __restrict__ H2, const float* __restrict__ bias,
    unsigned short* __restrict__ R2, int nbS) {
  const int b = blockIdx.x;
  const bool knn = (b >= nbS);
  const int* cnt = knn ? cnt_k : cnt_s;
  const int* slots = knn ? slots_k : slots_s;
  const float* dinv = knn ? dinv_k : dinv_s;
  const int cap = knn ? SLOT_K : SLOT_S;
  const int colOff = knn ? CO : 0;
  const int wv = threadIdx.x >> 6, lane = threadIdx.x & 63;
  const int c = (knn ? b - nbS : b) * 4 + wv;
  if (c >= NN || lane >= CO) return;
  const float dc = dinv[c];
  float acc = dc * bf2f(H2[(size_t)c * CO + lane]);
  int n = cnt[c]; if (n > cap) n = cap;
  const int* sl = slots + (size_t)c * cap;
  int e = 0;
  for (; e + 4 <= n; e += 4) {
    const int r0 = sl[e], r1 = sl[e + 1], r2 = sl[e + 2], r3 = sl[e + 3];
    const float d0 = dinv[r0], d1 = dinv[r1], d2 = dinv[r2], d3 = dinv[r3];
    acc += d0 * bf2f(H2[(size_t)r0 * CO + lane]) + d1 * bf2f(H2[(size_t)r1 * CO + lane])
         + d2 * bf2f(H2[(size_t)r2 * CO + lane]) + d3 * bf2f(H2[(size_t)r3 * CO + lane]);
  }
  for (; e < n; ++e) {
    const int r = sl[e];
    acc += dinv[r] * bf2f(H2[(size_t)r * CO + lane]);
  }
  R2[(size_t)c * 80 + colOff + lane] = f2bf(dc * acc + bias[lane]);   // no relu
}

// ---------------- head: logits = R2 @ Wlin^T + blin; log_softmax ----------------
__global__ __launch_bounds__(256) void k_final(const unsigned short* __restrict__ R2,
    const float* __restrict__ Wlin, const float* __restrict__ blin,
    float* __restrict__ out) {
  __shared__ float rw[32 * 81];   // 32 nodes x 80 (+1 pad)
  __shared__ float wl[40 * 81];   // 40 x 80 (+1 pad)
  __shared__ float bl[40];
  const int t = threadIdx.x;
  const int n0 = blockIdx.x * 32;   // 3125*32 = 100000 exactly
  for (int i = t; i < 2560; i += 256) rw[(i / 80) * 81 + (i % 80)] = bf2f(R2[(size_t)n0 * 80 + i]);
  for (int i = t; i < 3200; i += 256) wl[(i / 80) * 81 + (i % 80)] = Wlin[i];
  if (t < 40) bl[t] = blin[t];
  __syncthreads();
  const int nl = t >> 3, jg = t & 7;
  const int j0 = jg * 5;
  float lg[5];
#pragma unroll
  for (int jj = 0; jj < 5; ++jj) lg[jj] = bl[j0 + jj];
#pragma unroll 4
  for (int k = 0; k < 80; ++k) {
    const float v = rw[nl * 81 + k];
#pragma unroll
    for (int jj = 0; jj < 5; ++jj) lg[jj] += v * wl[(j0 + jj) * 81 + k];
  }
  float mx = lg[0];
#pragma unroll
  for (int jj = 1; jj < 5; ++jj) mx = fmaxf(mx, lg[jj]);
  mx = fmaxf(mx, __shfl_xor(mx, 1));
  mx = fmaxf(mx, __shfl_xor(mx, 2));
  mx = fmaxf(mx, __shfl_xor(mx, 4));
  float s = 0.f;
#pragma unroll
  for (int jj = 0; jj < 5; ++jj) s += expf(lg[jj] - mx);
  s += __shfl_xor(s, 1);
  s += __shfl_xor(s, 2);
  s += __shfl_xor(s, 4);
  const float lse = mx + logf(s);
  const int n = n0 + nl;
#pragma unroll
  for (int jj = 0; jj < 5; ++jj) out[(size_t)n * CO + j0 + jj] = lg[jj] - lse;
}

extern "C" void kernel_launch(void* const* d_in, const int* in_sizes, int n_in,
                              void* d_out, int out_size, void* d_ws, size_t ws_size,
                              hipStream_t stream) {
  const float* x  = (const float*)d_in[0];
  const int* ei   = (const int*)d_in[1];   // [2][E]: row0 = src, row1 = tgt
  const int* eik  = (const int*)d_in[2];
  const float* W1 = (const float*)d_in[3];
  const float* b1 = (const float*)d_in[4];
  const float* W2 = (const float*)d_in[5];
  const float* b2 = (const float*)d_in[6];
  const float* Wl = (const float*)d_in[7];
  const float* bl = (const float*)d_in[8];
  float* out = (float*)d_out;
  const int E  = in_sizes[1] / 2;
  const int EK = in_sizes[2] / 2;

  // workspace layout (~129 MB), 256B-aligned slots
  char* p = (char*)d_ws;
  size_t off = 0;
  auto alloc = [&](size_t bytes) -> void* {
    void* r = (void*)(p + off);
    off += (bytes + 255) & ~(size_t)255;
    return r;
  };
  int* deg_s = (int*)alloc((size_t)NN * 4);
  int* deg_k = (int*)alloc((size_t)NN * 4);
  void* zbuf = alloc(256);                 // zero redirect target for OOB tiles
  const size_t zero_span = off;            // memset covers deg_s, deg_k, zbuf
  float* dinv_s = (float*)alloc((size_t)NN * 4);
  float* dinv_k = (float*)alloc((size_t)NN * 4);
  unsigned short* W1T = (unsigned short*)alloc((size_t)HID * KP1 * 2);
  unsigned short* W2T = (unsigned short*)alloc((size_t)48 * K2 * 2);
  int* slots_s = (int*)alloc((size_t)NN * SLOT_S * 4);   // 32 MB
  int* slots_k = (int*)alloc((size_t)NN * SLOT_K * 4);   // 9.6 MB
  unsigned short* H1b = (unsigned short*)alloc((size_t)NN * HID * 2);   // 25.6 MB
  unsigned short* R1b = (unsigned short*)alloc((size_t)NN * K2 * 2);    // 51.2 MB
  unsigned short* H2b = (unsigned short*)alloc((size_t)NN * CO * 2);    // 8 MB
  unsigned short* R2  = H1b;   // alias: H1b dead after agg1; R2 = [NN x 80] bf16 (16 MB)

  hipMemsetAsync(d_ws, 0, zero_span, stream);

  // single-pass count+place for both graphs (fused launch)
  const int nbS = (E + 1023) / 1024;
  const int nbK = (EK + 1023) / 1024;
  k_slot<<<nbS + nbK, 256, 0, stream>>>(ei, E, nbS, deg_s, slots_s, eik, EK, deg_k, slots_k);
  k_dinv<<<(NN + 255) / 256, 256, 0, stream>>>(deg_s, deg_k, dinv_s, dinv_k);

  // weights -> bf16, B-operand (k-contiguous) layout
  k_w1t<<<(HID * KP1) / 256, 256, 0, stream>>>(W1, W1T);
  k_w2t<<<(48 * K2) / 256, 256, 0, stream>>>(W2, W2T);

  // layer 1: shared GEMM, fused dual aggregation into R1b halves
  k_gemm1<<<(NN + 127) / 128, 256, 0, stream>>>(x, W1T, (const float*)zbuf, H1b);
  const int nbAgg = (NN + 3) / 4;
  k_agg1<<<2 * nbAgg, 256, 0, stream>>>(deg_s, slots_s, dinv_s, deg_k, slots_k, dinv_k,
                                        H1b, b1, R1b, nbAgg);

  // layer 2: shared GEMM, fused dual aggregation into R2 halves
  k_gemm2<<<(NN + 127) / 128, 256, 0, stream>>>(R1b, W2T, (const unsigned short*)zbuf, H2b);
  k_agg2<<<2 * nbAgg, 256, 0, stream>>>(deg_s, slots_s, dinv_s, deg_k, slots_k, dinv_k,
                                        H2b, b2, R2, nbAgg);

  // head
  k_final<<<NN / 32, 256, 0, stream>>>(R2, Wl, bl, out);
}

// Round 3
// 793.824 us; speedup vs baseline: 1.5088x; 1.1932x over previous
//
#include <hip/hip_runtime.h>
#include <stdint.h>

// Problem constants (match reference)
#define NN   100000   // nodes
#define FIN  500      // input features
#define HID  128      // hidden
#define KP1  512      // FIN padded to mult of 32 for MFMA K-loop
#define K2   256      // 2*HID (GEMM2 K)
#define CO   40       // classes
#define NBUCK 391     // ceil(NN/256) coarse buckets (target>>8)
#define CAPB_S 9216   // structural bucket capacity (mean 8184, +11 sigma)
#define CAPB_K 1536   // knn bucket capacity (mean 1279, +7 sigma)

typedef __attribute__((ext_vector_type(8))) short short8;
typedef __attribute__((ext_vector_type(4))) float float4v;
typedef __attribute__((address_space(3))) unsigned int as3_u32;
typedef __attribute__((address_space(1))) unsigned int as1_u32;

__device__ __forceinline__ unsigned short f2bf(float f) {
  unsigned u = __float_as_uint(f);
  u = u + 0x7fffu + ((u >> 16) & 1u);   // RNE
  return (unsigned short)(u >> 16);
}
__device__ __forceinline__ float bf2f(unsigned short s) {
  return __uint_as_float(((unsigned)s) << 16);
}
__device__ __forceinline__ void gl_lds16(const void* g, void* l) {
  __builtin_amdgcn_global_load_lds((const as1_u32*)g, (as3_u32*)l, 16, 0, 0);
}

// ---------------- phase 1: bin edges by target>>8 (both graphs fused) ----------------
__global__ __launch_bounds__(256) void k_bin(
    const int* __restrict__ ei, int nS, int nb1S, int* __restrict__ gcur_s, int* __restrict__ gbin_s,
    const int* __restrict__ eik, int nK, int* __restrict__ gcur_k, int* __restrict__ gbin_k) {
  __shared__ int cnt[NBUCK];
  __shared__ int base[NBUCK];
  const int b = blockIdx.x;
  const bool knn = (b >= nb1S);
  const int* src = knn ? eik      : ei;
  const int* tgt = knn ? eik + nK : ei + nS;
  const int n    = knn ? nK : nS;
  int* gcur      = knn ? gcur_k : gcur_s;
  int* gbin      = knn ? gbin_k : gbin_s;
  const int capb = knn ? CAPB_K : CAPB_S;
  const int ebase = (knn ? b - nb1S : b) * 4096;
  const int t = threadIdx.x;

  for (int i = t; i < NBUCK; i += 256) cnt[i] = 0;
  __syncthreads();
  int s[16], g[16];
#pragma unroll
  for (int i = 0; i < 16; ++i) {
    const int e = ebase + i * 256 + t;
    const bool v = e < n;
    s[i] = v ? src[e] : 0;
    g[i] = v ? tgt[e] : -1;
    if (v) atomicAdd(&cnt[g[i] >> 8], 1);
  }
  __syncthreads();
  for (int i = t; i < NBUCK; i += 256) {       // reserve global space, reset local cursor
    const int c = cnt[i];
    base[i] = c ? atomicAdd(&gcur[i], c) : 0;
    cnt[i] = 0;
  }
  __syncthreads();
#pragma unroll
  for (int i = 0; i < 16; ++i) {
    if (g[i] >= 0) {
      const int bkt = g[i] >> 8;
      const int pos = base[bkt] + atomicAdd(&cnt[bkt], 1);
      if (pos < capb) gbin[bkt * capb + pos] = (s[i] << 8) | (g[i] & 255);
    }
  }
}

// ---------------- exclusive scan of bucket totals (2 blocks: structural, knn) ----------------
__global__ __launch_bounds__(512) void k_bscan(const int* __restrict__ gcur_s, int* __restrict__ bscan_s,
                                               const int* __restrict__ gcur_k, int* __restrict__ bscan_k) {
  __shared__ int sd[512];
  const int* gcur = blockIdx.x ? gcur_k : gcur_s;
  int* bscan      = blockIdx.x ? bscan_k : bscan_s;
  const int t = threadIdx.x;
  const int v = (t < NBUCK) ? gcur[t] : 0;
  sd[t] = v;
  __syncthreads();
  for (int off = 1; off < 512; off <<= 1) {
    const int x = (t >= off) ? sd[t - off] : 0;
    __syncthreads(); sd[t] += x; __syncthreads();
  }
  if (t < NBUCK) bscan[t] = sd[t] - v;   // exclusive
}

// ---------------- phase 2: per-bucket exact CSR + dinv (both graphs fused) ----------------
__global__ __launch_bounds__(256) void k_csr(
    const int* __restrict__ gcur_s, const int* __restrict__ gbin_s, const int* __restrict__ bscan_s,
    int* __restrict__ rp_s, int* __restrict__ col_s, float* __restrict__ dinv_s,
    const int* __restrict__ gcur_k, const int* __restrict__ gbin_k, const int* __restrict__ bscan_k,
    int* __restrict__ rp_k, int* __restrict__ col_k, float* __restrict__ dinv_k) {
  __shared__ int cnt[256];
  __shared__ int base[256];
  const int b0 = blockIdx.x;
  const bool knn = (b0 >= NBUCK);
  const int b = knn ? b0 - NBUCK : b0;
  const int* gcur  = knn ? gcur_k  : gcur_s;
  const int* gbin  = knn ? gbin_k  : gbin_s;
  const int* bscan = knn ? bscan_k : bscan_s;
  int* rp    = knn ? rp_k   : rp_s;
  int* col   = knn ? col_k  : col_s;
  float* dinv = knn ? dinv_k : dinv_s;
  const int capb = knn ? CAPB_K : CAPB_S;
  const int t = threadIdx.x;
  int nB = gcur[b]; if (nB > capb) nB = capb;
  const int gb0 = b * capb;
  const int gbase = bscan[b];

  cnt[t] = 0;
  __syncthreads();
  for (int i = t; i < nB; i += 256) atomicAdd(&cnt[gbin[gb0 + i] & 255], 1);
  __syncthreads();
  const int myc = cnt[t];
  base[t] = myc;
  __syncthreads();
  for (int off = 1; off < 256; off <<= 1) {   // inclusive Hillis-Steele
    const int x = (t >= off) ? base[t - off] : 0;
    __syncthreads(); base[t] += x; __syncthreads();
  }
  const int excl = base[t] - myc;
  const int tg = b * 256 + t;
  if (tg < NN) { rp[tg] = gbase + excl; dinv[tg] = rsqrtf((float)(myc + 1)); }
  if (tg == NN) rp[NN] = gbase + excl;        // only in last bucket (t=160)
  __syncthreads();
  base[t] = excl; cnt[t] = 0;
  __syncthreads();
  for (int i = t; i < nB; i += 256) {
    const int e = gbin[gb0 + i];
    const int tl = e & 255;
    const int pos = atomicAdd(&cnt[tl], 1);
    col[gbase + base[tl] + pos] = e >> 8;
  }
}

// ---------------- weight convert/transpose ----------------
__global__ void k_w1t(const float* __restrict__ W1, unsigned short* __restrict__ W1T) {
  int idx = blockIdx.x * 256 + threadIdx.x;      // 128*512
  int n = idx >> 9, k = idx & 511;
  float v = (k < FIN) ? W1[k * HID + n] : 0.f;
  W1T[idx] = f2bf(v);
}
__global__ void k_w2t(const float* __restrict__ W2, unsigned short* __restrict__ W2T) {
  int idx = blockIdx.x * 256 + threadIdx.x;      // 48*256
  int n = idx >> 8, k = idx & 255;
  float v = (n < CO) ? W2[k * CO + n] : 0.f;
  W2T[idx] = f2bf(v);
}

// ---------------- GEMM1: H1b = bf16(x @ W1)  [NN x 128] ----------------
__global__ __launch_bounds__(256) void k_gemm1(const float* __restrict__ x,
    const unsigned short* __restrict__ W1T, const float* __restrict__ zbuf,
    unsigned short* __restrict__ H1b) {
  __shared__ float Als[1024 * 4];          // chunk = kg4*128+m, 4 floats each (16B)
  __shared__ unsigned short Bls[512 * 8];  // chunk = kg8*128+n, 8 bf16 each (16B)
  const int t = threadIdx.x;
  const int wv = t >> 6, lane = t & 63;
  const int qd = lane >> 4, mr = lane & 15;
  const int m0 = blockIdx.x * 128;

  float4v acc[2][8];
  const float4v zf4 = {0.f, 0.f, 0.f, 0.f};
#pragma unroll
  for (int a = 0; a < 2; ++a)
#pragma unroll
    for (int b = 0; b < 8; ++b) acc[a][b] = zf4;

  for (int kk = 0; kk < 16; ++kk) {
    const int k0 = kk * 32;
    __syncthreads();
#pragma unroll
    for (int i = 0; i < 4; ++i) {
      const int cb = (wv * 4 + i) * 64;
      const int q = cb + lane;
      const int kg = q >> 7, m = q & 127;
      const int gm = m0 + m, kb = k0 + kg * 4;   // 500 % 4 == 0 -> never straddles
      const float* gp = (gm < NN && kb < FIN) ? (x + (size_t)gm * FIN + kb) : zbuf;
      gl_lds16(gp, &Als[cb * 4]);
    }
#pragma unroll
    for (int i = 0; i < 2; ++i) {
      const int cb = (wv * 2 + i) * 64;
      const int q = cb + lane;
      const int kg = q >> 7, n = q & 127;
      const unsigned short* gp = W1T + n * KP1 + k0 + kg * 8;
      gl_lds16(gp, &Bls[cb * 8]);
    }
    __syncthreads();
    short8 af[2];
#pragma unroll
    for (int rt = 0; rt < 2; ++rt) {   // A frag: A[m=lane&15][k=qd*8+j]
      const int m = wv * 32 + rt * 16 + mr;
      const float4v a0 = *(const float4v*)&Als[((2 * qd) * 128 + m) * 4];
      const float4v a1 = *(const float4v*)&Als[((2 * qd + 1) * 128 + m) * 4];
      short8 f;
      f[0] = (short)f2bf(a0[0]); f[1] = (short)f2bf(a0[1]);
      f[2] = (short)f2bf(a0[2]); f[3] = (short)f2bf(a0[3]);
      f[4] = (short)f2bf(a1[0]); f[5] = (short)f2bf(a1[1]);
      f[6] = (short)f2bf(a1[2]); f[7] = (short)f2bf(a1[3]);
      af[rt] = f;
    }
#pragma unroll
    for (int ct = 0; ct < 8; ++ct) {   // B frag: B[k=qd*8+j][n=lane&15]
      const short8 bf = *(const short8*)&Bls[(qd * 128 + ct * 16 + mr) * 8];
      acc[0][ct] = __builtin_amdgcn_mfma_f32_16x16x32_bf16(af[0], bf, acc[0][ct], 0, 0, 0);
      acc[1][ct] = __builtin_amdgcn_mfma_f32_16x16x32_bf16(af[1], bf, acc[1][ct], 0, 0, 0);
    }
  }
  // C/D layout: col = lane&15, row = (lane>>4)*4 + j
#pragma unroll
  for (int rt = 0; rt < 2; ++rt) {
    const int rb = m0 + wv * 32 + rt * 16 + qd * 4;
#pragma unroll
    for (int ct = 0; ct < 8; ++ct) {
      const int col = ct * 16 + mr;
#pragma unroll
      for (int j = 0; j < 4; ++j) {
        const int r = rb + j;
        if (r < NN) H1b[(size_t)r * HID + col] = f2bf(acc[rt][ct][j]);
      }
    }
  }
}

// ---------------- GEMM2: H2b = bf16(R1b @ W2)  [NN x 40] ----------------
__global__ __launch_bounds__(256) void k_gemm2(const unsigned short* __restrict__ R1b,
    const unsigned short* __restrict__ W2T, const unsigned short* __restrict__ zbuf,
    unsigned short* __restrict__ H2b) {
  __shared__ unsigned short Als[512 * 8];  // chunk = kg8*128+m
  __shared__ unsigned short Bls[192 * 8];  // chunk = kg8*48+n
  const int t = threadIdx.x;
  const int wv = t >> 6, lane = t & 63;
  const int qd = lane >> 4, mr = lane & 15;
  const int m0 = blockIdx.x * 128;

  float4v acc[2][3];
  const float4v zf4 = {0.f, 0.f, 0.f, 0.f};
#pragma unroll
  for (int a = 0; a < 2; ++a)
#pragma unroll
    for (int b = 0; b < 3; ++b) acc[a][b] = zf4;

  for (int kk = 0; kk < 8; ++kk) {
    const int k0 = kk * 32;
    __syncthreads();
#pragma unroll
    for (int i = 0; i < 2; ++i) {
      const int cb = (wv * 2 + i) * 64;
      const int q = cb + lane;
      const int kg = q >> 7, m = q & 127;
      const int gm = m0 + m;
      const unsigned short* gp = (gm < NN) ? (R1b + (size_t)gm * K2 + k0 + kg * 8) : zbuf;
      gl_lds16(gp, &Als[cb * 8]);
    }
    if (wv < 3) {   // 192 chunks = 3 wave-instrs
      const int cb = wv * 64;
      const int q = cb + lane;
      const int kg = q / 48, n = q % 48;
      const unsigned short* gp = W2T + n * K2 + k0 + kg * 8;
      gl_lds16(gp, &Bls[cb * 8]);
    }
    __syncthreads();
    short8 af[2];
#pragma unroll
    for (int rt = 0; rt < 2; ++rt)
      af[rt] = *(const short8*)&Als[(qd * 128 + wv * 32 + rt * 16 + mr) * 8];
#pragma unroll
    for (int ct = 0; ct < 3; ++ct) {
      const short8 bf = *(const short8*)&Bls[(qd * 48 + ct * 16 + mr) * 8];
      acc[0][ct] = __builtin_amdgcn_mfma_f32_16x16x32_bf16(af[0], bf, acc[0][ct], 0, 0, 0);
      acc[1][ct] = __builtin_amdgcn_mfma_f32_16x16x32_bf16(af[1], bf, acc[1][ct], 0, 0, 0);
    }
  }
#pragma unroll
  for (int rt = 0; rt < 2; ++rt) {
    const int rb = m0 + wv * 32 + rt * 16 + qd * 4;
#pragma unroll
    for (int ct = 0; ct < 3; ++ct) {
      const int col = ct * 16 + mr;
      if (col < CO) {
#pragma unroll
        for (int j = 0; j < 4; ++j) {
          const int r = rb + j;
          if (r < NN) H2b[(size_t)r * CO + col] = f2bf(acc[rt][ct][j]);
        }
      }
    }
  }
}

// ---------------- layer-1 aggregation (both graphs fused): wave per node, 128 cols ----------------
__global__ __launch_bounds__(256) void k_agg1(
    const int* __restrict__ rp_s, const int* __restrict__ col_s, const float* __restrict__ dinv_s,
    const int* __restrict__ rp_k, const int* __restrict__ col_k, const float* __restrict__ dinv_k,
    const unsigned short* __restrict__ H, const float* __restrict__ bias,
    unsigned short* __restrict__ out, int nbS) {
  const int b = blockIdx.x;
  const bool knn = (b >= nbS);
  const int* rp = knn ? rp_k : rp_s;
  const int* ci = knn ? col_k : col_s;
  const float* dinv = knn ? dinv_k : dinv_s;
  const int colOff = knn ? HID : 0;
  const int wv = threadIdx.x >> 6, lane = threadIdx.x & 63;
  const int c = (knn ? b - nbS : b) * 4 + wv;
  if (c >= NN) return;
  const float dc = dinv[c];
  const unsigned pc = ((const unsigned*)(H + (size_t)c * HID))[lane];
  float ax = dc * bf2f((unsigned short)(pc & 0xffffu));   // self loop
  float ay = dc * bf2f((unsigned short)(pc >> 16));
  int e = rp[c];
  const int e1 = rp[c + 1];
  for (; e + 4 <= e1; e += 4) {
    const int r0 = ci[e], r1 = ci[e + 1], r2 = ci[e + 2], r3 = ci[e + 3];
    const float d0 = dinv[r0], d1 = dinv[r1], d2 = dinv[r2], d3 = dinv[r3];
    const unsigned p0 = ((const unsigned*)(H + (size_t)r0 * HID))[lane];
    const unsigned p1 = ((const unsigned*)(H + (size_t)r1 * HID))[lane];
    const unsigned p2 = ((const unsigned*)(H + (size_t)r2 * HID))[lane];
    const unsigned p3 = ((const unsigned*)(H + (size_t)r3 * HID))[lane];
    ax += d0 * bf2f((unsigned short)(p0 & 0xffffu)) + d1 * bf2f((unsigned short)(p1 & 0xffffu))
        + d2 * bf2f((unsigned short)(p2 & 0xffffu)) + d3 * bf2f((unsigned short)(p3 & 0xffffu));
    ay += d0 * bf2f((unsigned short)(p0 >> 16)) + d1 * bf2f((unsigned short)(p1 >> 16))
        + d2 * bf2f((unsigned short)(p2 >> 16)) + d3 * bf2f((unsigned short)(p3 >> 16));
  }
  for (; e < e1; ++e) {
    const int r = ci[e];
    const float d = dinv[r];
    const unsigned pr = ((const unsigned*)(H + (size_t)r * HID))[lane];
    ax += d * bf2f((unsigned short)(pr & 0xffffu));
    ay += d * bf2f((unsigned short)(pr >> 16));
  }
  const float2 bb = ((const float2*)bias)[lane];
  const float o0 = fmaxf(dc * ax + bb.x, 0.f);   // relu
  const float o1 = fmaxf(dc * ay + bb.y, 0.f);
  const unsigned pk = (unsigned)f2bf(o0) | ((unsigned)f2bf(o1) << 16);
  ((unsigned*)(out + (size_t)c * (2 * HID) + colOff))[lane] = pk;
}

// ---------------- layer-2 aggregation (both graphs fused): wave per node, lanes 0..39 ----------------
__global__ __launch_bounds__(256) void k_agg2(
    const int* __restrict__ rp_s, const int* __restrict__ col_s, const float* __restrict__ dinv_s,
    const int* __restrict__ rp_k, const int* __restrict__ col_k, const float* __restrict__ dinv_k,
    const unsigned short* __restrict__ H2, const float* __restrict__ bias,
    unsigned short* __restrict__ R2, int nbS) {
  const int b = blockIdx.x;
  const bool knn = (b >= nbS);
  const int* rp = knn ? rp_k : rp_s;
  const int* ci = knn ? col_k : col_s;
  const float* dinv = knn ? dinv_k : dinv_s;
  const int colOff = knn ? CO : 0;
  const int wv = threadIdx.x >> 6, lane = threadIdx.x & 63;
  const int c = (knn ? b - nbS : b) * 4 + wv;
  if (c >= NN || lane >= CO) return;
  const float dc = dinv[c];
  float acc = dc * bf2f(H2[(size_t)c * CO + lane]);
  int e = rp[c];
  const int e1 = rp[c + 1];
  for (; e + 4 <= e1; e += 4) {
    const int r0 = ci[e], r1 = ci[e + 1], r2 = ci[e + 2], r3 = ci[e + 3];
    const float d0 = dinv[r0], d1 = dinv[r1], d2 = dinv[r2], d3 = dinv[r3];
    acc += d0 * bf2f(H2[(size_t)r0 * CO + lane]) + d1 * bf2f(H2[(size_t)r1 * CO + lane])
         + d2 * bf2f(H2[(size_t)r2 * CO + lane]) + d3 * bf2f(H2[(size_t)r3 * CO + lane]);
  }
  for (; e < e1; ++e) {
    const int r = ci[e];
    acc += dinv[r] * bf2f(H2[(size_t)r * CO + lane]);
  }
  R2[(size_t)c * 80 + colOff + lane] = f2bf(dc * acc + bias[lane]);   // no relu
}

// ---------------- head: logits = R2 @ Wlin^T + blin; log_softmax ----------------
__global__ __launch_bounds__(256) void k_final(const unsigned short* __restrict__ R2,
    const float* __restrict__ Wlin, const float* __restrict__ blin,
    float* __restrict__ out) {
  __shared__ float rw[32 * 81];   // 32 nodes x 80 (+1 pad)
  __shared__ float wl[40 * 81];   // 40 x 80 (+1 pad)
  __shared__ float bl[40];
  const int t = threadIdx.x;
  const int n0 = blockIdx.x * 32;   // 3125*32 = 100000 exactly
  for (int i = t; i < 2560; i += 256) rw[(i / 80) * 81 + (i % 80)] = bf2f(R2[(size_t)n0 * 80 + i]);
  for (int i = t; i < 3200; i += 256) wl[(i / 80) * 81 + (i % 80)] = Wlin[i];
  if (t < 40) bl[t] = blin[t];
  __syncthreads();
  const int nl = t >> 3, jg = t & 7;
  const int j0 = jg * 5;
  float lg[5];
#pragma unroll
  for (int jj = 0; jj < 5; ++jj) lg[jj] = bl[j0 + jj];
#pragma unroll 4
  for (int k = 0; k < 80; ++k) {
    const float v = rw[nl * 81 + k];
#pragma unroll
    for (int jj = 0; jj < 5; ++jj) lg[jj] += v * wl[(j0 + jj) * 81 + k];
  }
  float mx = lg[0];
#pragma unroll
  for (int jj = 1; jj < 5; ++jj) mx = fmaxf(mx, lg[jj]);
  mx = fmaxf(mx, __shfl_xor(mx, 1));
  mx = fmaxf(mx, __shfl_xor(mx, 2));
  mx = fmaxf(mx, __shfl_xor(mx, 4));
  float s = 0.f;
#pragma unroll
  for (int jj = 0; jj < 5; ++jj) s += expf(lg[jj] - mx);
  s += __shfl_xor(s, 1);
  s += __shfl_xor(s, 2);
  s += __shfl_xor(s, 4);
  const float lse = mx + logf(s);
  const int n = n0 + nl;
#pragma unroll
  for (int jj = 0; jj < 5; ++jj) out[(size_t)n * CO + j0 + jj] = lg[jj] - lse;
}

extern "C" void kernel_launch(void* const* d_in, const int* in_sizes, int n_in,
                              void* d_out, int out_size, void* d_ws, size_t ws_size,
                              hipStream_t stream) {
  const float* x  = (const float*)d_in[0];
  const int* ei   = (const int*)d_in[1];   // [2][E]: row0 = src, row1 = tgt
  const int* eik  = (const int*)d_in[2];
  const float* W1 = (const float*)d_in[3];
  const float* b1 = (const float*)d_in[4];
  const float* W2 = (const float*)d_in[5];
  const float* b2 = (const float*)d_in[6];
  const float* Wl = (const float*)d_in[7];
  const float* bl = (const float*)d_in[8];
  float* out = (float*)d_out;
  const int E  = in_sizes[1] / 2;
  const int EK = in_sizes[2] / 2;

  // workspace layout (~120 MB), 256B-aligned slots
  char* p = (char*)d_ws;
  size_t off = 0;
  auto alloc = [&](size_t bytes) -> void* {
    void* r = (void*)(p + off);
    off += (bytes + 255) & ~(size_t)255;
    return r;
  };
  int* gcur_s = (int*)alloc((size_t)NBUCK * 4);
  int* gcur_k = (int*)alloc((size_t)NBUCK * 4);
  void* zbuf = alloc(256);                 // zero redirect target for OOB tiles
  const size_t zero_span = off;            // memset covers gcur_s, gcur_k, zbuf
  int* bscan_s = (int*)alloc((size_t)NBUCK * 4);
  int* bscan_k = (int*)alloc((size_t)NBUCK * 4);
  float* dinv_s = (float*)alloc((size_t)NN * 4);
  float* dinv_k = (float*)alloc((size_t)NN * 4);
  int* rp_s = (int*)alloc((size_t)(NN + 1) * 4);
  int* rp_k = (int*)alloc((size_t)(NN + 1) * 4);
  unsigned short* W1T = (unsigned short*)alloc((size_t)HID * KP1 * 2);
  unsigned short* W2T = (unsigned short*)alloc((size_t)48 * K2 * 2);
  int* gbin_s = (int*)alloc((size_t)NBUCK * CAPB_S * 4);   // 14.4 MB
  int* gbin_k = (int*)alloc((size_t)NBUCK * CAPB_K * 4);   // 2.4 MB
  int* col_s = (int*)alloc((size_t)E * 4);                 // 12.8 MB
  int* col_k = (int*)alloc((size_t)EK * 4);                // 2 MB
  unsigned short* H1b = (unsigned short*)alloc((size_t)NN * HID * 2);   // 25.6 MB
  unsigned short* R1b = (unsigned short*)alloc((size_t)NN * K2 * 2);    // 51.2 MB
  unsigned short* H2b = (unsigned short*)alloc((size_t)NN * CO * 2);    // 8 MB
  unsigned short* R2  = H1b;   // alias: H1b dead after agg1; R2 = [NN x 80] bf16 (16 MB)

  hipMemsetAsync(d_ws, 0, zero_span, stream);

  // CSR build: bin -> scan -> per-bucket exact CSR (+dinv)
  const int nb1S = (E + 4095) / 4096;
  const int nb1K = (EK + 4095) / 4096;
  k_bin<<<nb1S + nb1K, 256, 0, stream>>>(ei, E, nb1S, gcur_s, gbin_s, eik, EK, gcur_k, gbin_k);
  k_bscan<<<2, 512, 0, stream>>>(gcur_s, bscan_s, gcur_k, bscan_k);
  k_csr<<<2 * NBUCK, 256, 0, stream>>>(gcur_s, gbin_s, bscan_s, rp_s, col_s, dinv_s,
                                       gcur_k, gbin_k, bscan_k, rp_k, col_k, dinv_k);

  // weights -> bf16, B-operand (k-contiguous) layout
  k_w1t<<<(HID * KP1) / 256, 256, 0, stream>>>(W1, W1T);
  k_w2t<<<(48 * K2) / 256, 256, 0, stream>>>(W2, W2T);

  // layer 1: shared GEMM, fused dual aggregation into R1b halves
  k_gemm1<<<(NN + 127) / 128, 256, 0, stream>>>(x, W1T, (const float*)zbuf, H1b);
  const int nbAgg = (NN + 3) / 4;
  k_agg1<<<2 * nbAgg, 256, 0, stream>>>(rp_s, col_s, dinv_s, rp_k, col_k, dinv_k,
                                        H1b, b1, R1b, nbAgg);

  // layer 2: shared GEMM, fused dual aggregation into R2 halves
  k_gemm2<<<(NN + 127) / 128, 256, 0, stream>>>(R1b, W2T, (const unsigned short*)zbuf, H2b);
  k_agg2<<<2 * nbAgg, 256, 0, stream>>>(rp_s, col_s, dinv_s, rp_k, col_k, dinv_k,
                                        H2b, b2, R2, nbAgg);

  // head
  k_final<<<NN / 32, 256, 0, stream>>>(R2, Wl, bl, out);
}

// Round 4
// 761.209 us; speedup vs baseline: 1.5735x; 1.0428x over previous
//
#include <hip/hip_runtime.h>
#include <stdint.h>

// Problem constants (match reference)
#define NN   100000   // nodes
#define FIN  500      // input features
#define HID  128      // hidden
#define KP1  512      // FIN padded to mult of 32 for MFMA K-loop
#define K2   256      // 2*HID (GEMM2 K)
#define CO   40       // classes
#define NPQ  80       // folded tail GEMM N (P|Q)
#define NBUCK 391     // ceil(NN/256) coarse buckets (target>>8)
#define CAPB_S 9216   // structural bucket capacity (mean 8184, +11 sigma)
#define CAPB_K 1536   // knn bucket capacity (mean 1279, +7 sigma)

typedef __attribute__((ext_vector_type(8))) short short8;
typedef __attribute__((ext_vector_type(4))) float float4v;
typedef __attribute__((address_space(3))) unsigned int as3_u32;
typedef __attribute__((address_space(1))) unsigned int as1_u32;

__device__ __forceinline__ unsigned short f2bf(float f) {
  unsigned u = __float_as_uint(f);
  u = u + 0x7fffu + ((u >> 16) & 1u);   // RNE
  return (unsigned short)(u >> 16);
}
__device__ __forceinline__ float bf2f(unsigned short s) {
  return __uint_as_float(((unsigned)s) << 16);
}
__device__ __forceinline__ void gl_lds16(const void* g, void* l) {
  __builtin_amdgcn_global_load_lds((const as1_u32*)g, (as3_u32*)l, 16, 0, 0);
}

// ---------------- phase 1: bin edges by target>>8 (both graphs fused) ----------------
__global__ __launch_bounds__(256) void k_bin(
    const int* __restrict__ ei, int nS, int nb1S, int* __restrict__ gcur_s, int* __restrict__ gbin_s,
    const int* __restrict__ eik, int nK, int* __restrict__ gcur_k, int* __restrict__ gbin_k) {
  __shared__ int cnt[NBUCK];
  __shared__ int base[NBUCK];
  const int b = blockIdx.x;
  const bool knn = (b >= nb1S);
  const int* src = knn ? eik      : ei;
  const int* tgt = knn ? eik + nK : ei + nS;
  const int n    = knn ? nK : nS;
  int* gcur      = knn ? gcur_k : gcur_s;
  int* gbin      = knn ? gbin_k : gbin_s;
  const int capb = knn ? CAPB_K : CAPB_S;
  const int ebase = (knn ? b - nb1S : b) * 4096;
  const int t = threadIdx.x;

  for (int i = t; i < NBUCK; i += 256) cnt[i] = 0;
  __syncthreads();
  int s[16], g[16];
#pragma unroll
  for (int i = 0; i < 16; ++i) {
    const int e = ebase + i * 256 + t;
    const bool v = e < n;
    s[i] = v ? src[e] : 0;
    g[i] = v ? tgt[e] : -1;
    if (v) atomicAdd(&cnt[g[i] >> 8], 1);
  }
  __syncthreads();
  for (int i = t; i < NBUCK; i += 256) {       // reserve global space, reset local cursor
    const int c = cnt[i];
    base[i] = c ? atomicAdd(&gcur[i], c) : 0;
    cnt[i] = 0;
  }
  __syncthreads();
#pragma unroll
  for (int i = 0; i < 16; ++i) {
    if (g[i] >= 0) {
      const int bkt = g[i] >> 8;
      const int pos = base[bkt] + atomicAdd(&cnt[bkt], 1);
      if (pos < capb) gbin[bkt * capb + pos] = (s[i] << 8) | (g[i] & 255);
    }
  }
}

// ---------------- exclusive scan of bucket totals (2 blocks: structural, knn) ----------------
__global__ __launch_bounds__(512) void k_bscan(const int* __restrict__ gcur_s, int* __restrict__ bscan_s,
                                               const int* __restrict__ gcur_k, int* __restrict__ bscan_k) {
  __shared__ int sd[512];
  const int* gcur = blockIdx.x ? gcur_k : gcur_s;
  int* bscan      = blockIdx.x ? bscan_k : bscan_s;
  const int t = threadIdx.x;
  const int v = (t < NBUCK) ? gcur[t] : 0;
  sd[t] = v;
  __syncthreads();
  for (int off = 1; off < 512; off <<= 1) {
    const int x = (t >= off) ? sd[t - off] : 0;
    __syncthreads(); sd[t] += x; __syncthreads();
  }
  if (t < NBUCK) bscan[t] = sd[t] - v;   // exclusive
}

// ---------------- phase 2: per-bucket exact CSR + dinv (both graphs fused) ----------------
// colw entries: {src, w} — w filled later by k_fuse
__global__ __launch_bounds__(256) void k_csr(
    const int* __restrict__ gcur_s, const int* __restrict__ gbin_s, const int* __restrict__ bscan_s,
    int* __restrict__ rp_s, int2* __restrict__ colw_s, float* __restrict__ dinv_s,
    const int* __restrict__ gcur_k, const int* __restrict__ gbin_k, const int* __restrict__ bscan_k,
    int* __restrict__ rp_k, int2* __restrict__ colw_k, float* __restrict__ dinv_k) {
  __shared__ int cnt[256];
  __shared__ int base[256];
  const int b0 = blockIdx.x;
  const bool knn = (b0 >= NBUCK);
  const int b = knn ? b0 - NBUCK : b0;
  const int* gcur  = knn ? gcur_k  : gcur_s;
  const int* gbin  = knn ? gbin_k  : gbin_s;
  const int* bscan = knn ? bscan_k : bscan_s;
  int* rp     = knn ? rp_k   : rp_s;
  int2* colw  = knn ? colw_k : colw_s;
  float* dinv = knn ? dinv_k : dinv_s;
  const int capb = knn ? CAPB_K : CAPB_S;
  const int t = threadIdx.x;
  int nB = gcur[b]; if (nB > capb) nB = capb;
  const int gb0 = b * capb;
  const int gbase = bscan[b];

  cnt[t] = 0;
  __syncthreads();
  for (int i = t; i < nB; i += 256) atomicAdd(&cnt[gbin[gb0 + i] & 255], 1);
  __syncthreads();
  const int myc = cnt[t];
  base[t] = myc;
  __syncthreads();
  for (int off = 1; off < 256; off <<= 1) {   // inclusive Hillis-Steele
    const int x = (t >= off) ? base[t - off] : 0;
    __syncthreads(); base[t] += x; __syncthreads();
  }
  const int excl = base[t] - myc;
  const int tg = b * 256 + t;
  if (tg < NN) { rp[tg] = gbase + excl; dinv[tg] = rsqrtf((float)(myc + 1)); }
  if (tg == NN) rp[NN] = gbase + excl;        // only in last bucket (t=160)
  __syncthreads();
  base[t] = excl; cnt[t] = 0;
  __syncthreads();
  for (int i = t; i < nB; i += 256) {
    const int e = gbin[gb0 + i];
    const int tl = e & 255;
    const int pos = atomicAdd(&cnt[tl], 1);
    colw[gbase + base[tl] + pos] = make_int2(e >> 8, 0);
  }
}

// ---------------- fill w = dinv[src] into colw (both graphs) ----------------
__global__ __launch_bounds__(256) void k_fuse(
    int2* __restrict__ colw_s, const float* __restrict__ dinv_s, int nS, int nbF,
    int2* __restrict__ colw_k, const float* __restrict__ dinv_k, int nK) {
  const int b = blockIdx.x;
  if (b < nbF) {
    const int i = b * 256 + threadIdx.x;
    if (i < nS) {
      const int s = colw_s[i].x;
      colw_s[i].y = __float_as_int(dinv_s[s]);
    }
  } else {
    const int i = (b - nbF) * 256 + threadIdx.x;
    if (i < nK) {
      const int s = colw_k[i].x;
      colw_k[i].y = __float_as_int(dinv_k[s]);
    }
  }
}

// ---------------- weight prep ----------------
__global__ void k_w1t(const float* __restrict__ W1, unsigned short* __restrict__ W1T) {
  int idx = blockIdx.x * 256 + threadIdx.x;      // 128*512
  int n = idx >> 9, k = idx & 511;
  float v = (k < FIN) ? W1[k * HID + n] : 0.f;
  W1T[idx] = f2bf(v);
}
// WpqT[n][k], n<80, k<256: n<40 -> P col o=n (Wlin left), n>=40 -> Q col o=n-40 (Wlin right)
// cb[o] = blin[o] + sum_j b2[j]*(Wl[o][j] + Wl[o][40+j])
__global__ void k_wpq(const float* __restrict__ W2, const float* __restrict__ Wl,
                      const float* __restrict__ b2, const float* __restrict__ bl,
                      unsigned short* __restrict__ WpqT, float* __restrict__ cb) {
  const int idx = blockIdx.x * 256 + threadIdx.x;   // 80*256 = 20480
  const int n = idx >> 8, k = idx & 255;
  const int o = (n < CO) ? n : n - CO;
  const int joff = (n < CO) ? 0 : CO;
  float s = 0.f;
#pragma unroll 8
  for (int j = 0; j < CO; ++j) s += W2[k * CO + j] * Wl[o * NPQ + joff + j];
  WpqT[n * K2 + k] = f2bf(s);
  if (blockIdx.x == 0 && threadIdx.x < CO) {
    const int oo = threadIdx.x;
    float c = bl[oo];
    for (int j = 0; j < CO; ++j) c += b2[j] * (Wl[oo * NPQ + j] + Wl[oo * NPQ + CO + j]);
    cb[oo] = c;
  }
}

// ---------------- GEMM1: H1b = bf16(x @ W1)  [NN x 128] ----------------
__global__ __launch_bounds__(256) void k_gemm1(const float* __restrict__ x,
    const unsigned short* __restrict__ W1T, const float* __restrict__ zbuf,
    unsigned short* __restrict__ H1b) {
  __shared__ float Als[1024 * 4];          // chunk = kg4*128+m, 4 floats each (16B)
  __shared__ unsigned short Bls[512 * 8];  // chunk = kg8*128+n, 8 bf16 each (16B)
  const int t = threadIdx.x;
  const int wv = t >> 6, lane = t & 63;
  const int qd = lane >> 4, mr = lane & 15;
  const int m0 = blockIdx.x * 128;

  float4v acc[2][8];
  const float4v zf4 = {0.f, 0.f, 0.f, 0.f};
#pragma unroll
  for (int a = 0; a < 2; ++a)
#pragma unroll
    for (int b = 0; b < 8; ++b) acc[a][b] = zf4;

  for (int kk = 0; kk < 16; ++kk) {
    const int k0 = kk * 32;
    __syncthreads();
#pragma unroll
    for (int i = 0; i < 4; ++i) {
      const int cb = (wv * 4 + i) * 64;
      const int q = cb + lane;
      const int kg = q >> 7, m = q & 127;
      const int gm = m0 + m, kb = k0 + kg * 4;   // 500 % 4 == 0 -> never straddles
      const float* gp = (gm < NN && kb < FIN) ? (x + (size_t)gm * FIN + kb) : zbuf;
      gl_lds16(gp, &Als[cb * 4]);
    }
#pragma unroll
    for (int i = 0; i < 2; ++i) {
      const int cb = (wv * 2 + i) * 64;
      const int q = cb + lane;
      const int kg = q >> 7, n = q & 127;
      const unsigned short* gp = W1T + n * KP1 + k0 + kg * 8;
      gl_lds16(gp, &Bls[cb * 8]);
    }
    __syncthreads();
    short8 af[2];
#pragma unroll
    for (int rt = 0; rt < 2; ++rt) {   // A frag: A[m=lane&15][k=qd*8+j]
      const int m = wv * 32 + rt * 16 + mr;
      const float4v a0 = *(const float4v*)&Als[((2 * qd) * 128 + m) * 4];
      const float4v a1 = *(const float4v*)&Als[((2 * qd + 1) * 128 + m) * 4];
      short8 f;
      f[0] = (short)f2bf(a0[0]); f[1] = (short)f2bf(a0[1]);
      f[2] = (short)f2bf(a0[2]); f[3] = (short)f2bf(a0[3]);
      f[4] = (short)f2bf(a1[0]); f[5] = (short)f2bf(a1[1]);
      f[6] = (short)f2bf(a1[2]); f[7] = (short)f2bf(a1[3]);
      af[rt] = f;
    }
#pragma unroll
    for (int ct = 0; ct < 8; ++ct) {   // B frag: B[k=qd*8+j][n=lane&15]
      const short8 bf = *(const short8*)&Bls[(qd * 128 + ct * 16 + mr) * 8];
      acc[0][ct] = __builtin_amdgcn_mfma_f32_16x16x32_bf16(af[0], bf, acc[0][ct], 0, 0, 0);
      acc[1][ct] = __builtin_amdgcn_mfma_f32_16x16x32_bf16(af[1], bf, acc[1][ct], 0, 0, 0);
    }
  }
  // C/D layout: col = lane&15, row = (lane>>4)*4 + j
#pragma unroll
  for (int rt = 0; rt < 2; ++rt) {
    const int rb = m0 + wv * 32 + rt * 16 + qd * 4;
#pragma unroll
    for (int ct = 0; ct < 8; ++ct) {
      const int col = ct * 16 + mr;
#pragma unroll
      for (int j = 0; j < 4; ++j) {
        const int r = rb + j;
        if (r < NN) H1b[(size_t)r * HID + col] = f2bf(acc[rt][ct][j]);
      }
    }
  }
}

// ---------------- GEMM2: PQ = bf16(R1b @ Wpq)  [NN x 80] ----------------
__global__ __launch_bounds__(256) void k_gemm2(const unsigned short* __restrict__ R1b,
    const unsigned short* __restrict__ WpqT, const unsigned short* __restrict__ zbuf,
    unsigned short* __restrict__ PQ) {
  __shared__ unsigned short Als[512 * 8];  // chunk = kg8*128+m
  __shared__ unsigned short Bls[320 * 8];  // chunk = kg8*80+n
  const int t = threadIdx.x;
  const int wv = t >> 6, lane = t & 63;
  const int qd = lane >> 4, mr = lane & 15;
  const int m0 = blockIdx.x * 128;

  float4v acc[2][5];
  const float4v zf4 = {0.f, 0.f, 0.f, 0.f};
#pragma unroll
  for (int a = 0; a < 2; ++a)
#pragma unroll
    for (int b = 0; b < 5; ++b) acc[a][b] = zf4;

  for (int kk = 0; kk < 8; ++kk) {
    const int k0 = kk * 32;
    __syncthreads();
#pragma unroll
    for (int i = 0; i < 2; ++i) {
      const int cb = (wv * 2 + i) * 64;
      const int q = cb + lane;
      const int kg = q >> 7, m = q & 127;
      const int gm = m0 + m;
      const unsigned short* gp = (gm < NN) ? (R1b + (size_t)gm * K2 + k0 + kg * 8) : zbuf;
      gl_lds16(gp, &Als[cb * 8]);
    }
    // B: 320 chunks = 5 wave-instrs (wv 0..3 do inst wv; wv 0 also inst 4)
    {
      const int cb = wv * 64;
      const int q = cb + lane;
      const int kg = q / 80, n = q % 80;
      gl_lds16(WpqT + n * K2 + k0 + kg * 8, &Bls[cb * 8]);
      if (wv == 0) {
        const int cb2 = 4 * 64;
        const int q2 = cb2 + lane;
        const int kg2 = q2 / 80, n2 = q2 % 80;
        gl_lds16(WpqT + n2 * K2 + k0 + kg2 * 8, &Bls[cb2 * 8]);
      }
    }
    __syncthreads();
    short8 af[2];
#pragma unroll
    for (int rt = 0; rt < 2; ++rt)
      af[rt] = *(const short8*)&Als[(qd * 128 + wv * 32 + rt * 16 + mr) * 8];
#pragma unroll
    for (int ct = 0; ct < 5; ++ct) {
      const short8 bf = *(const short8*)&Bls[(qd * 80 + ct * 16 + mr) * 8];
      acc[0][ct] = __builtin_amdgcn_mfma_f32_16x16x32_bf16(af[0], bf, acc[0][ct], 0, 0, 0);
      acc[1][ct] = __builtin_amdgcn_mfma_f32_16x16x32_bf16(af[1], bf, acc[1][ct], 0, 0, 0);
    }
  }
#pragma unroll
  for (int rt = 0; rt < 2; ++rt) {
    const int rb = m0 + wv * 32 + rt * 16 + qd * 4;
#pragma unroll
    for (int ct = 0; ct < 5; ++ct) {
      const int col = ct * 16 + mr;
#pragma unroll
      for (int j = 0; j < 4; ++j) {
        const int r = rb + j;
        if (r < NN) PQ[(size_t)r * NPQ + col] = f2bf(acc[rt][ct][j]);
      }
    }
  }
}

// ---------------- gather helper: 128-col bf16 rows, unroll 8 + index prefetch ----------------
__device__ __forceinline__ void agg_row128(const int2* __restrict__ cw, int e0, int e1,
    const unsigned* __restrict__ H32, int lane, float& ax, float& ay) {
  const int nb = (e1 - e0) & ~7;
  int e = e0;
  if (nb) {
    int2 q[8];
#pragma unroll
    for (int j = 0; j < 8; ++j) q[j] = cw[e + j];
    for (int base = 0; base < nb; base += 8) {
      int2 qn[8];
      const bool more = (base + 8 < nb);
      if (more) {
#pragma unroll
        for (int j = 0; j < 8; ++j) qn[j] = cw[e + base + 8 + j];
      }
#pragma unroll
      for (int j = 0; j < 8; ++j) {
        const unsigned d = H32[(size_t)q[j].x * 64 + lane];
        const float w = __int_as_float(q[j].y);
        ax += w * __uint_as_float(d << 16);
        ay += w * __uint_as_float(d & 0xffff0000u);
      }
      if (more) {
#pragma unroll
        for (int j = 0; j < 8; ++j) q[j] = qn[j];
      }
    }
    e += nb;
  }
  for (; e < e1; ++e) {
    const int2 q = cw[e];
    const unsigned d = H32[(size_t)q.x * 64 + lane];
    const float w = __int_as_float(q.y);
    ax += w * __uint_as_float(d << 16);
    ay += w * __uint_as_float(d & 0xffff0000u);
  }
}

// ---------------- layer-1 aggregation: one wave per node, BOTH graphs ----------------
__global__ __launch_bounds__(256) void k_agg1(
    const int* __restrict__ rp_s, const int2* __restrict__ colw_s, const float* __restrict__ dinv_s,
    const int* __restrict__ rp_k, const int2* __restrict__ colw_k, const float* __restrict__ dinv_k,
    const unsigned short* __restrict__ H, const float* __restrict__ bias,
    unsigned short* __restrict__ out) {
  const int wv = threadIdx.x >> 6, lane = threadIdx.x & 63;
  const int c = blockIdx.x * 4 + wv;
  if (c >= NN) return;
  const unsigned* H32 = (const unsigned*)H;
  const float dcs = dinv_s[c];
  const float dck = dinv_k[c];
  const unsigned pc = H32[(size_t)c * 64 + lane];
  const float slo = __uint_as_float(pc << 16);
  const float shi = __uint_as_float(pc & 0xffff0000u);
  float ax = dcs * slo, ay = dcs * shi;   // structural self
  float bx = dck * slo, by = dck * shi;   // knn self
  agg_row128(colw_s, rp_s[c], rp_s[c + 1], H32, lane, ax, ay);
  agg_row128(colw_k, rp_k[c], rp_k[c + 1], H32, lane, bx, by);
  const float2 bb = ((const float2*)bias)[lane];
  const float o0 = fmaxf(dcs * ax + bb.x, 0.f);
  const float o1 = fmaxf(dcs * ay + bb.y, 0.f);
  const float o2 = fmaxf(dck * bx + bb.x, 0.f);
  const float o3 = fmaxf(dck * by + bb.y, 0.f);
  unsigned* orow = (unsigned*)(out + (size_t)c * K2);
  orow[lane]      = (unsigned)f2bf(o0) | ((unsigned)f2bf(o1) << 16);
  orow[64 + lane] = (unsigned)f2bf(o2) | ((unsigned)f2bf(o3) << 16);
}

// ---------------- tail: logits = agg_s(P) + agg_k(Q) + cb; log_softmax ----------------
// wave per node; 3 groups of 20 lanes gather edges in parallel (strided), combine via shfl
__global__ __launch_bounds__(256) void k_aggf(
    const int* __restrict__ rp_s, const int2* __restrict__ colw_s, const float* __restrict__ dinv_s,
    const int* __restrict__ rp_k, const int2* __restrict__ colw_k, const float* __restrict__ dinv_k,
    const unsigned short* __restrict__ PQ, const float* __restrict__ cb,
    float* __restrict__ out) {
  const int wv = threadIdx.x >> 6, lane = threadIdx.x & 63;
  const int c = blockIdx.x * 4 + wv;
  if (c >= NN) return;
  const unsigned* PQ32 = (const unsigned*)PQ;
  const int g = lane / 20;        // 0..2 active groups (lanes 60-63 idle)
  const int l = lane % 20;        // dword index: P dwords 0-19, Q dwords 20-39
  float sx = 0.f, sy = 0.f, kx = 0.f, ky = 0.f;
  if (g < 3) {
    // structural edges -> P
    {
      const int e1 = rp_s[c + 1];
      int e = rp_s[c] + g;
      for (; e + 9 < e1; e += 12) {
        const int2 q0 = colw_s[e], q1 = colw_s[e + 3], q2 = colw_s[e + 6], q3 = colw_s[e + 9];
        const unsigned d0 = PQ32[(size_t)q0.x * 40 + l];
        const unsigned d1 = PQ32[(size_t)q1.x * 40 + l];
        const unsigned d2 = PQ32[(size_t)q2.x * 40 + l];
        const unsigned d3 = PQ32[(size_t)q3.x * 40 + l];
        const float w0 = __int_as_float(q0.y), w1 = __int_as_float(q1.y);
        const float w2 = __int_as_float(q2.y), w3 = __int_as_float(q3.y);
        sx += w0 * __uint_as_float(d0 << 16) + w1 * __uint_as_float(d1 << 16)
            + w2 * __uint_as_float(d2 << 16) + w3 * __uint_as_float(d3 << 16);
        sy += w0 * __uint_as_float(d0 & 0xffff0000u) + w1 * __uint_as_float(d1 & 0xffff0000u)
            + w2 * __uint_as_float(d2 & 0xffff0000u) + w3 * __uint_as_float(d3 & 0xffff0000u);
      }
      for (; e < e1; e += 3) {
        const int2 q = colw_s[e];
        const unsigned d = PQ32[(size_t)q.x * 40 + l];
        const float w = __int_as_float(q.y);
        sx += w * __uint_as_float(d << 16);
        sy += w * __uint_as_float(d & 0xffff0000u);
      }
    }
    // knn edges -> Q
    {
      const int e1 = rp_k[c + 1];
      int e = rp_k[c] + g;
      for (; e < e1; e += 3) {
        const int2 q = colw_k[e];
        const unsigned d = PQ32[(size_t)q.x * 40 + 20 + l];
        const float w = __int_as_float(q.y);
        kx += w * __uint_as_float(d << 16);
        ky += w * __uint_as_float(d & 0xffff0000u);
      }
    }
  }
  // combine 3 group partials into lanes 0-19
  sx += __shfl(sx, lane + 20) + __shfl(sx, lane + 40);
  sy += __shfl(sy, lane + 20) + __shfl(sy, lane + 40);
  kx += __shfl(kx, lane + 20) + __shfl(kx, lane + 40);
  ky += __shfl(ky, lane + 20) + __shfl(ky, lane + 40);

  float lo = 0.f, hi = 0.f;
  if (lane < 20) {
    const float dcs = dinv_s[c], dck = dinv_k[c];
    const unsigned dP = PQ32[(size_t)c * 40 + lane];
    const unsigned dQ = PQ32[(size_t)c * 40 + 20 + lane];
    const float2 cbb = ((const float2*)cb)[lane];
    lo = dcs * (sx + dcs * __uint_as_float(dP << 16))
       + dck * (kx + dck * __uint_as_float(dQ << 16)) + cbb.x;
    hi = dcs * (sy + dcs * __uint_as_float(dP & 0xffff0000u))
       + dck * (ky + dck * __uint_as_float(dQ & 0xffff0000u)) + cbb.y;
  }
  // log_softmax over 40 (lanes 0-19 hold pairs)
  float m = (lane < 20) ? fmaxf(lo, hi) : -3.4e38f;
#pragma unroll
  for (int off = 1; off < 64; off <<= 1) m = fmaxf(m, __shfl_xor(m, off));
  float s = (lane < 20) ? (expf(lo - m) + expf(hi - m)) : 0.f;
#pragma unroll
  for (int off = 1; off < 64; off <<= 1) s += __shfl_xor(s, off);
  const float lse = m + logf(s);
  if (lane < 20) {
    float2 o; o.x = lo - lse; o.y = hi - lse;
    ((float2*)(out + (size_t)c * CO))[lane] = o;
  }
}

extern "C" void kernel_launch(void* const* d_in, const int* in_sizes, int n_in,
                              void* d_out, int out_size, void* d_ws, size_t ws_size,
                              hipStream_t stream) {
  const float* x  = (const float*)d_in[0];
  const int* ei   = (const int*)d_in[1];   // [2][E]: row0 = src, row1 = tgt
  const int* eik  = (const int*)d_in[2];
  const float* W1 = (const float*)d_in[3];
  const float* b1 = (const float*)d_in[4];
  const float* W2 = (const float*)d_in[5];
  const float* b2 = (const float*)d_in[6];
  const float* Wl = (const float*)d_in[7];
  const float* bl = (const float*)d_in[8];
  float* out = (float*)d_out;
  const int E  = in_sizes[1] / 2;
  const int EK = in_sizes[2] / 2;

  // workspace layout (~125 MB), 256B-aligned slots
  char* p = (char*)d_ws;
  size_t off = 0;
  auto alloc = [&](size_t bytes) -> void* {
    void* r = (void*)(p + off);
    off += (bytes + 255) & ~(size_t)255;
    return r;
  };
  int* gcur_s = (int*)alloc((size_t)NBUCK * 4);
  int* gcur_k = (int*)alloc((size_t)NBUCK * 4);
  void* zbuf = alloc(256);                 // zero redirect target for OOB tiles
  const size_t zero_span = off;            // memset covers gcur_s, gcur_k, zbuf
  int* bscan_s = (int*)alloc((size_t)NBUCK * 4);
  int* bscan_k = (int*)alloc((size_t)NBUCK * 4);
  float* dinv_s = (float*)alloc((size_t)NN * 4);
  float* dinv_k = (float*)alloc((size_t)NN * 4);
  int* rp_s = (int*)alloc((size_t)(NN + 1) * 4);
  int* rp_k = (int*)alloc((size_t)(NN + 1) * 4);
  unsigned short* W1T = (unsigned short*)alloc((size_t)HID * KP1 * 2);
  unsigned short* WpqT = (unsigned short*)alloc((size_t)NPQ * K2 * 2);
  float* cbv = (float*)alloc((size_t)CO * 4);
  int* gbin_s = (int*)alloc((size_t)NBUCK * CAPB_S * 4);    // 14.4 MB
  int* gbin_k = (int*)alloc((size_t)NBUCK * CAPB_K * 4);    // 2.4 MB
  int2* colw_s = (int2*)alloc((size_t)E * 8);               // 25.6 MB
  int2* colw_k = (int2*)alloc((size_t)EK * 8);              // 4 MB
  unsigned short* H1b = (unsigned short*)alloc((size_t)NN * HID * 2);   // 25.6 MB
  unsigned short* R1b = (unsigned short*)alloc((size_t)NN * K2 * 2);    // 51.2 MB
  unsigned short* PQ = H1b;   // alias: H1b dead after agg1; PQ = [NN x 80] bf16 (16 MB)

  hipMemsetAsync(d_ws, 0, zero_span, stream);

  // CSR build: bin -> scan -> per-bucket exact CSR (+dinv) -> fuse dinv[src] into edges
  const int nb1S = (E + 4095) / 4096;
  const int nb1K = (EK + 4095) / 4096;
  k_bin<<<nb1S + nb1K, 256, 0, stream>>>(ei, E, nb1S, gcur_s, gbin_s, eik, EK, gcur_k, gbin_k);
  k_bscan<<<2, 512, 0, stream>>>(gcur_s, bscan_s, gcur_k, bscan_k);
  k_csr<<<2 * NBUCK, 256, 0, stream>>>(gcur_s, gbin_s, bscan_s, rp_s, colw_s, dinv_s,
                                       gcur_k, gbin_k, bscan_k, rp_k, colw_k, dinv_k);
  const int nbF = (E + 255) / 256;
  const int nbFk = (EK + 255) / 256;
  k_fuse<<<nbF + nbFk, 256, 0, stream>>>(colw_s, dinv_s, E, nbF, colw_k, dinv_k, EK);

  // weight prep
  k_w1t<<<(HID * KP1) / 256, 256, 0, stream>>>(W1, W1T);
  k_wpq<<<NPQ, 256, 0, stream>>>(W2, Wl, b2, bl, WpqT, cbv);

  // layer 1: shared GEMM, fused dual aggregation (one wave per node)
  k_gemm1<<<(NN + 127) / 128, 256, 0, stream>>>(x, W1T, (const float*)zbuf, H1b);
  const int nbAgg = (NN + 3) / 4;
  k_agg1<<<nbAgg, 256, 0, stream>>>(rp_s, colw_s, dinv_s, rp_k, colw_k, dinv_k, H1b, b1, R1b);

  // folded tail: PQ GEMM + fused aggregation/log_softmax
  k_gemm2<<<(NN + 127) / 128, 256, 0, stream>>>(R1b, WpqT, (const unsigned short*)zbuf, PQ);
  k_aggf<<<nbAgg, 256, 0, stream>>>(rp_s, colw_s, dinv_s, rp_k, colw_k, dinv_k, PQ, cbv, out);
}